// Round 5
// baseline (412.332 us; speedup 1.0000x reference)
//
#include <hip/hip_runtime.h>
#include <math.h>

#define Bn 4
#define Tn 4096
#define Dn 1024
#define Nn 64
#define Rn 16
#define KCONV 4

#define TT2 32    // t-rows per prep block
#define KCH 32    // K-chunk (one 16x16x32 MFMA K-step)
#define SU 32     // scan chunk (steps per prefetch block)

typedef __attribute__((ext_vector_type(8))) short bf16x8;
typedef __attribute__((ext_vector_type(4))) float f32x4;
typedef __attribute__((ext_vector_type(2))) float f32x2;

__device__ __forceinline__ unsigned short bf16_rne(float f) {
    unsigned int u = __float_as_uint(f);
    unsigned int r = (u + 0x7fffu + ((u >> 16) & 1u)) >> 16;
    return (unsigned short)r;
}

// ---------------------------------------------------------------------------
// Layout v2 (round 5): intermediates live inside d_out as PACKED [t][n] blocks
// per 64-row tile, so every global access is wave-contiguous (no 4KB-stride
// gathers — round-4's TA floor).
// For tile t0' (64-aligned), region base R = (b*Tn + t0')*Dn (256KB of floats):
//   P (t,n)  -> O[R +        (t-t0')*64 + n]    floats [０,4096)   (rows 0-3)
//   Dl(t,n)  -> O[R + 4096 + (t-t0')*64 + n]    floats [4096,8192) (rows 4-7)
//   S (t,n)  -> O[R + 8192 + (t-t0')*64 + n]    floats [8192,12288)(rows 8-11)
// out_kernel only reads S of its own 64 rows (rows 8-11 of its region) and
// stages it fully before overwriting. Race-free, zero d_ws usage.
// ---------------------------------------------------------------------------

// ---------------------------------------------------------------------------
// Kernel 1 (MFMA bf16x3): fused conv + input proj + delta path.
// Only the epilogue write addresses changed for layout v2.
// ---------------------------------------------------------------------------
__global__ __launch_bounds__(128)
void prep_kernel(const float* __restrict__ x, const float* __restrict__ conv_w,
                 const float* __restrict__ in_w, const float* __restrict__ in_b,
                 const float* __restrict__ dt_w, const float* __restrict__ dt_b,
                 const float* __restrict__ tr_w,
                 float* __restrict__ O)
{
    __shared__ bf16x8 Axc_h[2][64], Axc_l[2][64];   // A = x+conv (hi/lo)
    __shared__ bf16x8 Axr_h[2][64], Axr_l[2][64];   // A = raw x  (hi/lo)
    __shared__ bf16x8 Bw_h[4][64],  Bw_l[4][64];    // B = in_w rows (hi/lo)
    __shared__ bf16x8 Bd_h[64],     Bd_l[64];       // B = dt_w rows (hi/lo)
    __shared__ float  AsS[TT2][17];                 // tanh activations
    __shared__ float  trS[Nn][17];                  // tr_w padded

    const int tid = threadIdx.x;
    const int b   = blockIdx.y;
    const int t0  = blockIdx.x * TT2;
    const int l   = tid & 63;
    const int w   = tid >> 6;

    const float* xb = x + (size_t)b * Tn * Dn;

    for (int idx = tid; idx < Nn * Rn; idx += 128)
        trS[idx >> 4][idx & 15] = tr_w[idx];

    const f32x4 z4 = {0.f, 0.f, 0.f, 0.f};
    f32x4 accP[4] = {z4, z4, z4, z4};
    f32x4 accG = z4;

    for (int kc = 0; kc < Dn / KCH; ++kc) {
        const int k0 = kc * KCH;
        __syncthreads();

        // ---- stage A fragments: conv + hi/lo split
        {
            const int m  = tid & 31;
            const int s  = tid >> 5;
            const int t  = t0 + m;
            const int gk = k0 + 8 * s;
            float v[4][8];
            #pragma unroll
            for (int dr = 0; dr < 4; ++dr) {
                int tp = t - 3 + dr;
                if (tp >= 0) {
                    float4 a  = *(const float4*)&xb[(size_t)tp * Dn + gk];
                    float4 bq = *(const float4*)&xb[(size_t)tp * Dn + gk + 4];
                    v[dr][0]=a.x;  v[dr][1]=a.y;  v[dr][2]=a.z;  v[dr][3]=a.w;
                    v[dr][4]=bq.x; v[dr][5]=bq.y; v[dr][6]=bq.z; v[dr][7]=bq.w;
                } else {
                    #pragma unroll
                    for (int k = 0; k < 8; ++k) v[dr][k] = 0.f;
                }
            }
            bf16x8 fch, fcl, frh, frl;
            #pragma unroll
            for (int k = 0; k < 8; ++k) {
                float4 cw = *(const float4*)&conv_w[(size_t)(gk + k) * 4];
                float xr = v[3][k];
                float xc = xr;
                xc = fmaf(v[0][k], cw.x, xc);
                xc = fmaf(v[1][k], cw.y, xc);
                xc = fmaf(v[2][k], cw.z, xc);
                xc = fmaf(v[3][k], cw.w, xc);
                unsigned short h; float hf;
                h = bf16_rne(xc); hf = __uint_as_float((unsigned)h << 16);
                fch[k] = (short)h; fcl[k] = (short)bf16_rne(xc - hf);
                h = bf16_rne(xr); hf = __uint_as_float((unsigned)h << 16);
                frh[k] = (short)h; frl[k] = (short)bf16_rne(xr - hf);
            }
            const int lane = (m & 15) | (s << 4), mt = m >> 4;
            Axc_h[mt][lane] = fch; Axc_l[mt][lane] = fcl;
            Axr_h[mt][lane] = frh; Axr_l[mt][lane] = frl;
        }
        // ---- stage B fragments
        #pragma unroll
        for (int rep = 0; rep < 2; ++rep) {
            int slot = tid + rep * 128;
            int n = slot & 63, s = slot >> 6;
            const float* wp = &in_w[(size_t)n * Dn + k0 + 8 * s];
            float4 a  = *(const float4*)wp;
            float4 bq = *(const float4*)(wp + 4);
            float wv[8] = {a.x, a.y, a.z, a.w, bq.x, bq.y, bq.z, bq.w};
            bf16x8 fh, fl;
            #pragma unroll
            for (int k = 0; k < 8; ++k) {
                unsigned short h = bf16_rne(wv[k]);
                float hf = __uint_as_float((unsigned)h << 16);
                fh[k] = (short)h; fl[k] = (short)bf16_rne(wv[k] - hf);
            }
            Bw_h[n >> 4][(n & 15) | (s << 4)] = fh;
            Bw_l[n >> 4][(n & 15) | (s << 4)] = fl;
        }
        if (tid < 64) {
            int r = tid & 15, s = tid >> 4;
            const float* wp = &dt_w[(size_t)r * Dn + k0 + 8 * s];
            float4 a  = *(const float4*)wp;
            float4 bq = *(const float4*)(wp + 4);
            float wv[8] = {a.x, a.y, a.z, a.w, bq.x, bq.y, bq.z, bq.w};
            bf16x8 fh, fl;
            #pragma unroll
            for (int k = 0; k < 8; ++k) {
                unsigned short h = bf16_rne(wv[k]);
                float hf = __uint_as_float((unsigned)h << 16);
                fh[k] = (short)h; fl[k] = (short)bf16_rne(wv[k] - hf);
            }
            Bd_h[tid] = fh; Bd_l[tid] = fl;
        }
        __syncthreads();

        // ---- MFMA phase: bf16x3 = Ah*Bh + Al*Bh + Ah*Bl
        bf16x8 axh = Axc_h[w][l], axl = Axc_l[w][l];
        bf16x8 arh = Axr_h[w][l], arl = Axr_l[w][l];
        #pragma unroll
        for (int nt = 0; nt < 4; ++nt) {
            bf16x8 bh = Bw_h[nt][l], bl = Bw_l[nt][l];
            accP[nt] = __builtin_amdgcn_mfma_f32_16x16x32_bf16(axh, bh, accP[nt], 0, 0, 0);
            accP[nt] = __builtin_amdgcn_mfma_f32_16x16x32_bf16(axl, bh, accP[nt], 0, 0, 0);
            accP[nt] = __builtin_amdgcn_mfma_f32_16x16x32_bf16(axh, bl, accP[nt], 0, 0, 0);
        }
        {
            bf16x8 bh = Bd_h[l], bl = Bd_l[l];
            accG = __builtin_amdgcn_mfma_f32_16x16x32_bf16(arh, bh, accG, 0, 0, 0);
            accG = __builtin_amdgcn_mfma_f32_16x16x32_bf16(arl, bh, accG, 0, 0, 0);
            accG = __builtin_amdgcn_mfma_f32_16x16x32_bf16(arh, bl, accG, 0, 0, 0);
        }
    }

    // ---- epilogue: As = tanh(G + dt_b); Dl = As @ tr_w.T; write P, Dl
    __syncthreads();
    #pragma unroll
    for (int i = 0; i < 4; ++i)
        AsS[16 * w + 4 * (l >> 4) + i][l & 15] = tanhf(accG[i] + dt_b[l & 15]);
    __syncthreads();

    float as_[4][16];
    #pragma unroll
    for (int i = 0; i < 4; ++i) {
        int mrow = 16 * w + 4 * (l >> 4) + i;
        #pragma unroll
        for (int j = 0; j < 4; ++j) {
            float4 q = *(const float4*)&AsS[mrow][4 * j];
            as_[i][4*j] = q.x; as_[i][4*j+1] = q.y;
            as_[i][4*j+2] = q.z; as_[i][4*j+3] = q.w;
        }
    }
    const int tile0 = t0 & ~63;        // 64-aligned tile base
    const int coff  = t0 & 63;         // local-t offset of this block's 32 rows
    const size_t base = (size_t)(b * Tn + tile0) * Dn;   // tile region
    #pragma unroll
    for (int nt = 0; nt < 4; ++nt) {
        int n = 16 * nt + (l & 15);
        float tw[16];
        #pragma unroll
        for (int j = 0; j < 4; ++j) {
            float4 q = *(const float4*)&trS[n][4 * j];
            tw[4*j] = q.x; tw[4*j+1] = q.y; tw[4*j+2] = q.z; tw[4*j+3] = q.w;
        }
        float ib = in_b[n];
        #pragma unroll
        for (int i = 0; i < 4; ++i) {
            int mrow = 16 * w + 4 * (l >> 4) + i;
            float dlv = 0.f;
            #pragma unroll
            for (int r = 0; r < 16; ++r) dlv = fmaf(as_[i][r], tw[r], dlv);
            // packed [t][n] write: lt = coff+mrow, n
            size_t a = base + (size_t)(coff + mrow) * 64 + n;
            O[a]        = accP[nt][i] + ib;   // P block
            O[a + 4096] = dlv;                // Dl block
        }
    }
}

// ---------------------------------------------------------------------------
// Kernel 2: sequential scan, coalesced layout-v2, LDS-staged, distance-2.
// grid (B), block 64 (1 wave). Lane n owns chain n.
//
// Round-4 post-mortem: 2212 cyc/chunk; residual over compute (~900) matches
// the TA gather floor of the [n][t] layout (24 VMEM instr x 64 lines). v2:
// all global accesses wave-contiguous (1KB/instr), chain access handled in
// LDS via ds_read2st64 (256B t-stride, bank-free), S transposed back through
// an LDS ping-pong and stored as 8 coalesced 1KB dwordx4 stores.
//
// vmcnt ledger (in-order counting; L=16 DMA loads, F=8 S-stores; iter c:
// issue L_{c+2} -> WAIT -> flush S_{c-1}(8 st) -> asm ds_reads + compute):
//   prologue: [L0 L1 L2]                WAIT(32) keeps L1,L2
//   c=1:      [L1 L2 L3]                WAIT(32) keeps L2,L3
//   steady c: [L_c S_{c-2} L_{c+1} S_{c-1} L_{c+2}] -> newer than L_c = 40
//             WAIT(40) keeps [S?,L_{c+1},S_{c-1},L_{c+2}] and drains L_c
//   c=126:    [L126 S124 L127 S125]     WAIT(32) drains L126
//   c=127:    [S124? L127 S125 S126]    WAIT(16) drains L127
// ---------------------------------------------------------------------------

typedef const __attribute__((address_space(1))) void GVoid;
typedef __attribute__((address_space(3))) void LVoid;
typedef __attribute__((address_space(3))) float LdsFloat;

#define WAITV(N) do {                                                    \
    asm volatile("s_waitcnt vmcnt(" #N ")" ::: "memory");                \
    __builtin_amdgcn_sched_barrier(0);                                   \
} while (0)

// Issue one chunk: P = 8KB contiguous, Dl = 8KB contiguous (at +4096 floats).
// Instr j: 64 lanes x 16B = 1KB contiguous global -> LDS linear [t][n].
__device__ __forceinline__ void issue_chunk(float* lds, const float* gbase, int n)
{
    const float* rp = gbase + n * 4;
    #pragma unroll
    for (int j = 0; j < 8; ++j)
        __builtin_amdgcn_global_load_lds((GVoid*)(rp + j * 256),
                                         (LVoid*)(lds + j * 256), 16, 0, 0);
    #pragma unroll
    for (int j = 0; j < 8; ++j)
        __builtin_amdgcn_global_load_lds((GVoid*)(rp + 4096 + j * 256),
                                         (LVoid*)(lds + 2048 + j * 256), 16, 0, 0);
}

// Flush previous chunk's S: LDS [t][n] (linear) -> 8 coalesced 1KB stores.
__device__ __forceinline__ void flush_s(const float* sb, float* sdst, int n)
{
    unsigned a = (unsigned)(size_t)(LdsFloat*)sb + (unsigned)(n * 16);
    f32x4 q[8];
    #pragma unroll
    for (int m = 0; m < 8; ++m)
        asm volatile("ds_read_b128 %0, %1 offset:%c2"
                     : "=&v"(q[m]) : "v"(a), "i"(m * 1024));
    asm volatile("s_waitcnt lgkmcnt(0)" ::: "memory");
    __builtin_amdgcn_sched_barrier(0);
    #pragma unroll
    for (int m = 0; m < 8; ++m)
        *(f32x4*)(sdst + m * 256 + n * 4) = q[m];
}

// Compute 32 steps. buf: [t][n] P (floats 0..2047) + Dl (2048..4095).
// Reads via ds_read2st64_b32 (t-stride = 256B = one st64 unit); writes S into
// sbuf [t][n] via ds_write2st64_b32. All DS ops in asm: the compiler cannot
// see them, so it cannot insert conservative vmcnt drains (round-3 lesson).
__device__ __forceinline__ void compute_chunk(const float* buf, float* sbuf,
                                              int n, float& st)
{
    const float L2E = 1.44269504088896340736f;
    unsigned a  = (unsigned)(size_t)(LdsFloat*)buf  + (unsigned)(n * 4);
    unsigned as = (unsigned)(size_t)(LdsFloat*)sbuf + (unsigned)(n * 4);
    f32x2 pr[16], dr[16];
    #pragma unroll
    for (int q = 0; q < 16; ++q)
        asm volatile("ds_read2st64_b32 %0, %1 offset0:%c2 offset1:%c3"
                     : "=&v"(pr[q]) : "v"(a), "i"(2 * q), "i"(2 * q + 1));
    #pragma unroll
    for (int q = 0; q < 16; ++q)
        asm volatile("ds_read2st64_b32 %0, %1 offset0:%c2 offset1:%c3"
                     : "=&v"(dr[q]) : "v"(a), "i"(32 + 2 * q), "i"(33 + 2 * q));
    asm volatile("s_waitcnt lgkmcnt(0)" ::: "memory");
    __builtin_amdgcn_sched_barrier(0);
    #pragma unroll
    for (int q = 0; q < 16; ++q) {
        f32x2 sv2;
        #pragma unroll
        for (int e = 0; e < 2; ++e) {
            float d = dr[q][e];
            float u = st + d;                                   // off critical path
            float x = __builtin_amdgcn_exp2f(fmaf(st, -L2E, -d * L2E));
            float r = __builtin_amdgcn_rcpf(1.f + x);
            st = fmaf(u, r, pr[q][e]);
            sv2[e] = st;
        }
        asm volatile("ds_write2st64_b32 %0, %1, %2 offset0:%c3 offset1:%c4"
                     :: "v"(as), "v"(sv2[0]), "v"(sv2[1]),
                        "i"(2 * q), "i"(2 * q + 1) : "memory");
    }
}

__global__ __launch_bounds__(64, 1)
void scan_kernel(float* __restrict__ O)
{
    __shared__ __align__(16) float buf[3][4096];    // P+Dl, 16KB per chunk buffer
    __shared__ __align__(16) float sbuf[2][2048];   // S ping-pong, 8KB each

    const int b = blockIdx.x;
    const int n = threadIdx.x;
    float* obase = O + (size_t)b * Tn * Dn;

    // chunk c: gbase = region of tile (c>>1) + half (c&1); P at +0, Dl at
    // +4096, S at +8192 (uniform offsets from gbase).
#define GB(c) (obase + (size_t)((c) >> 1) * (64 * Dn) + ((c) & 1) * 2048)

    float st = 0.f;
    float* b0 = buf[0]; float* b1 = buf[1]; float* b2 = buf[2];

    // ---- prologue: fill pipe (chunks 0,1,2), compute chunk 0
    issue_chunk(b0, GB(0), n);                 // L0
    issue_chunk(b1, GB(1), n);                 // L1
    issue_chunk(b2, GB(2), n);                 // L2
    WAITV(32);                                 // drain L0
    compute_chunk(b0, sbuf[0], n, st);         // c0 -> S0 in sbuf[0]
    { float* t = b0; b0 = b1; b1 = b2; b2 = t; }

    // ---- c = 1
    issue_chunk(b2, GB(3), n);                 // L3
    WAITV(32);                                 // drain L1
    flush_s(sbuf[0], GB(0) + 8192, n);         // store S0 (8 stores)
    compute_chunk(b0, sbuf[1], n, st);         // c1 -> sbuf[1]
    { float* t = b0; b0 = b1; b1 = b2; b2 = t; }

    // ---- steady state: c = 2..125
    #pragma unroll 1
    for (int c = 2; c <= 125; ++c) {
        issue_chunk(b2, GB(c + 2), n);         // L_{c+2}
        WAITV(40);                             // drain L_c
        flush_s(sbuf[(c - 1) & 1], GB(c - 1) + 8192, n);   // S_{c-1}
        compute_chunk(b0, sbuf[c & 1], n, st); // c -> sbuf[c&1]
        { float* t = b0; b0 = b1; b1 = b2; b2 = t; }
    }

    // ---- c = 126: no issue; queue [L126,S124,L127,S125] -> drain L126
    WAITV(32);
    flush_s(sbuf[1], GB(125) + 8192, n);       // S125
    compute_chunk(b0, sbuf[0], n, st);         // c126 -> sbuf[0]
    { float* t = b0; b0 = b1; b1 = b2; b2 = t; }

    // ---- c = 127: queue [L127,S125?,S126] -> newer than L127 = 16
    WAITV(16);
    flush_s(sbuf[0], GB(126) + 8192, n);       // S126
    compute_chunk(b0, sbuf[1], n, st);         // c127 -> sbuf[1]
    flush_s(sbuf[1], GB(127) + 8192, n);       // S127
#undef GB
}

// ---------------------------------------------------------------------------
// Kernel 3: output projection, in-place. grid (BT/64), block 256.
// Layout v2: S block is contiguous [t][n] at region + 8192 -> staging is a
// single fully-coalesced sweep.
// ---------------------------------------------------------------------------
__global__ __launch_bounds__(256)
void out_kernel(const float* __restrict__ out_w, const float* __restrict__ out_b,
                float* __restrict__ O)
{
    __shared__ float Ss[64][Nn + 4];   // Ss[t_local][n]
    __shared__ float wT[Nn][64 + 4];

    const int tid = threadIdx.x;
    const int r0  = blockIdx.x * 64;
    const int c   = tid & 15;
    const int g   = tid >> 4;
    const size_t br0 = (size_t)r0 * Dn;   // tile region base

    // stage S: contiguous block at br0 + 8192, float idx = tl*64 + nn
    for (int idx = tid; idx < 64 * 16; idx += 256) {
        int tl = idx >> 4, n4 = (idx & 15) * 4;
        float4 v = *(const float4*)&O[br0 + 8192 + (size_t)idx * 4];
        Ss[tl][n4 + 0] = v.x;
        Ss[tl][n4 + 1] = v.y;
        Ss[tl][n4 + 2] = v.z;
        Ss[tl][n4 + 3] = v.w;
    }
    __syncthreads();

    for (int cb = 0; cb < Dn / 64; ++cb) {
        const int d0 = cb * 64;
        for (int idx = tid; idx < Nn * 64 / 4; idx += 256) {
            int dl = idx >> 4, n4 = (idx & 15) * 4;
            float4 wv = *(const float4*)&out_w[(size_t)(d0 + dl) * Nn + n4];
            wT[n4 + 0][dl] = wv.x;
            wT[n4 + 1][dl] = wv.y;
            wT[n4 + 2][dl] = wv.z;
            wT[n4 + 3][dl] = wv.w;
        }
        __syncthreads();

        float acc[4][4] = {};
        #pragma unroll
        for (int kq = 0; kq < Nn; kq += 4) {
            float4 wv0 = *(const float4*)&wT[kq + 0][4 * c];
            float4 wv1 = *(const float4*)&wT[kq + 1][4 * c];
            float4 wv2 = *(const float4*)&wT[kq + 2][4 * c];
            float4 wv3 = *(const float4*)&wT[kq + 3][4 * c];
            #pragma unroll
            for (int i = 0; i < 4; ++i) {
                int row = g + 16 * i;
                float4 xv = *(const float4*)&Ss[row][kq];
                acc[i][0] = fmaf(xv.x, wv0.x, fmaf(xv.y, wv1.x, fmaf(xv.z, wv2.x, fmaf(xv.w, wv3.x, acc[i][0]))));
                acc[i][1] = fmaf(xv.x, wv0.y, fmaf(xv.y, wv1.y, fmaf(xv.z, wv2.y, fmaf(xv.w, wv3.y, acc[i][1]))));
                acc[i][2] = fmaf(xv.x, wv0.z, fmaf(xv.y, wv1.z, fmaf(xv.z, wv2.z, fmaf(xv.w, wv3.z, acc[i][2]))));
                acc[i][3] = fmaf(xv.x, wv0.w, fmaf(xv.y, wv1.w, fmaf(xv.z, wv2.w, fmaf(xv.w, wv3.w, acc[i][3]))));
            }
        }

        float4 bb = *(const float4*)&out_b[d0 + 4 * c];
        #pragma unroll
        for (int i = 0; i < 4; ++i) {
            int row = g + 16 * i;
            float4 o = make_float4(acc[i][0] + bb.x, acc[i][1] + bb.y,
                                   acc[i][2] + bb.z, acc[i][3] + bb.w);
            *(float4*)&O[(size_t)(r0 + row) * Dn + d0 + 4 * c] = o;
        }
        __syncthreads();
    }
}

extern "C" void kernel_launch(void* const* d_in, const int* in_sizes, int n_in,
                              void* d_out, int out_size, void* d_ws, size_t ws_size,
                              hipStream_t stream)
{
    const float* x      = (const float*)d_in[0];
    const float* conv_w = (const float*)d_in[1];
    const float* in_w   = (const float*)d_in[2];
    const float* in_b   = (const float*)d_in[3];
    const float* dt_w   = (const float*)d_in[4];
    const float* dt_b   = (const float*)d_in[5];
    const float* tr_w   = (const float*)d_in[6];
    const float* out_w  = (const float*)d_in[7];
    const float* out_b  = (const float*)d_in[8];
    float* O = (float*)d_out;
    (void)d_ws; (void)ws_size;

    dim3 g1(Tn / TT2, Bn);
    prep_kernel<<<g1, 128, 0, stream>>>(x, conv_w, in_w, in_b, dt_w, dt_b, tr_w, O);

    scan_kernel<<<dim3(Bn), 64, 0, stream>>>(O);

    out_kernel<<<dim3((Bn * Tn) / 64), 256, 0, stream>>>(out_w, out_b, O);
}

// Round 6
// 406.781 us; speedup vs baseline: 1.0136x; 1.0136x over previous
//
#include <hip/hip_runtime.h>
#include <math.h>

#define Bn 4
#define Tn 4096
#define Dn 1024
#define Nn 64
#define Rn 16
#define KCONV 4

#define TT2 64    // t-rows per prep block (64-row tiles, 4 waves)
#define KCH 32    // K-chunk (one 16x16x32 MFMA K-step)
#define SU 32     // scan chunk (steps per prefetch block)

typedef __attribute__((ext_vector_type(8))) short bf16x8;
typedef __attribute__((ext_vector_type(4))) float f32x4;

__device__ __forceinline__ unsigned short bf16_rne(float f) {
    unsigned int u = __float_as_uint(f);
    unsigned int r = (u + 0x7fffu + ((u >> 16) & 1u)) >> 16;
    return (unsigned short)r;
}

// Layout v1 (round-4 verified): intermediates live INSIDE d_out, TRANSPOSED
// per 64-row tile. For tile t0' = t & ~63:
//   element (t, n) of P  -> O[(b*Tn + t0' + n)*Dn +   0 + (t - t0')]
//   element (t, n) of Dl -> O[(b*Tn + t0' + n)*Dn +  64 + (t - t0')]
//   element (t, n) of S  -> O[(b*Tn + t0' + n)*Dn + 128 + (t - t0')]
// out_kernel only touches its own 64 rows before overwriting them.

// ---------------------------------------------------------------------------
// Kernel 1 (MFMA bf16x3): fused conv + input proj + delta path.
// Round-6 change: 64-row tiles (256 thr, 4 waves) — halves block count and
// halves the per-block B-matrix (in_w/dt_w) staging + bf16-split work.
// ---------------------------------------------------------------------------
__global__ __launch_bounds__(256)
void prep_kernel(const float* __restrict__ x, const float* __restrict__ conv_w,
                 const float* __restrict__ in_w, const float* __restrict__ in_b,
                 const float* __restrict__ dt_w, const float* __restrict__ dt_b,
                 const float* __restrict__ tr_w,
                 float* __restrict__ O)
{
    __shared__ bf16x8 Axc_h[4][64], Axc_l[4][64];   // A = x+conv (hi/lo), 4 M-tiles
    __shared__ bf16x8 Axr_h[4][64], Axr_l[4][64];   // A = raw x  (hi/lo)
    __shared__ bf16x8 Bw_h[4][64],  Bw_l[4][64];    // B = in_w rows (hi/lo)
    __shared__ bf16x8 Bd_h[64],     Bd_l[64];       // B = dt_w rows (hi/lo)
    __shared__ float  AsS[TT2][17];                 // tanh activations
    __shared__ float  trS[Nn][17];                  // tr_w padded

    const int tid = threadIdx.x;
    const int b   = blockIdx.y;
    const int t0  = blockIdx.x * TT2;               // 64-aligned
    const int l   = tid & 63;
    const int w   = tid >> 6;                       // wave 0..3

    const float* xb = x + (size_t)b * Tn * Dn;

    for (int idx = tid; idx < Nn * Rn; idx += 256)
        trS[idx >> 4][idx & 15] = tr_w[idx];

    const f32x4 z4 = {0.f, 0.f, 0.f, 0.f};
    f32x4 accP[4] = {z4, z4, z4, z4};
    f32x4 accG = z4;

    for (int kc = 0; kc < Dn / KCH; ++kc) {
        const int k0 = kc * KCH;
        __syncthreads();

        // ---- stage A fragments: 64 rows x 4 col-segs = 256 slots = 256 thr
        {
            const int m  = tid & 63;
            const int s  = tid >> 6;
            const int t  = t0 + m;
            const int gk = k0 + 8 * s;
            float v[4][8];
            #pragma unroll
            for (int dr = 0; dr < 4; ++dr) {
                int tp = t - 3 + dr;
                if (tp >= 0) {
                    float4 a  = *(const float4*)&xb[(size_t)tp * Dn + gk];
                    float4 bq = *(const float4*)&xb[(size_t)tp * Dn + gk + 4];
                    v[dr][0]=a.x;  v[dr][1]=a.y;  v[dr][2]=a.z;  v[dr][3]=a.w;
                    v[dr][4]=bq.x; v[dr][5]=bq.y; v[dr][6]=bq.z; v[dr][7]=bq.w;
                } else {
                    #pragma unroll
                    for (int k = 0; k < 8; ++k) v[dr][k] = 0.f;
                }
            }
            bf16x8 fch, fcl, frh, frl;
            #pragma unroll
            for (int k = 0; k < 8; ++k) {
                float4 cw = *(const float4*)&conv_w[(size_t)(gk + k) * 4];
                float xr = v[3][k];
                float xc = xr;
                xc = fmaf(v[0][k], cw.x, xc);
                xc = fmaf(v[1][k], cw.y, xc);
                xc = fmaf(v[2][k], cw.z, xc);
                xc = fmaf(v[3][k], cw.w, xc);
                unsigned short h; float hf;
                h = bf16_rne(xc); hf = __uint_as_float((unsigned)h << 16);
                fch[k] = (short)h; fcl[k] = (short)bf16_rne(xc - hf);
                h = bf16_rne(xr); hf = __uint_as_float((unsigned)h << 16);
                frh[k] = (short)h; frl[k] = (short)bf16_rne(xr - hf);
            }
            const int lane = (m & 15) | (s << 4), mt = m >> 4;   // mt 0..3
            Axc_h[mt][lane] = fch; Axc_l[mt][lane] = fcl;
            Axr_h[mt][lane] = frh; Axr_l[mt][lane] = frl;
        }
        // ---- stage B fragments: 64 n x 4 segs = 256 slots, single pass
        {
            int n = tid & 63, s = tid >> 6;
            const float* wp = &in_w[(size_t)n * Dn + k0 + 8 * s];
            float4 a  = *(const float4*)wp;
            float4 bq = *(const float4*)(wp + 4);
            float wv[8] = {a.x, a.y, a.z, a.w, bq.x, bq.y, bq.z, bq.w};
            bf16x8 fh, fl;
            #pragma unroll
            for (int k = 0; k < 8; ++k) {
                unsigned short h = bf16_rne(wv[k]);
                float hf = __uint_as_float((unsigned)h << 16);
                fh[k] = (short)h; fl[k] = (short)bf16_rne(wv[k] - hf);
            }
            Bw_h[n >> 4][(n & 15) | (s << 4)] = fh;
            Bw_l[n >> 4][(n & 15) | (s << 4)] = fl;
        }
        if (tid < 64) {
            int r = tid & 15, s = tid >> 4;
            const float* wp = &dt_w[(size_t)r * Dn + k0 + 8 * s];
            float4 a  = *(const float4*)wp;
            float4 bq = *(const float4*)(wp + 4);
            float wv[8] = {a.x, a.y, a.z, a.w, bq.x, bq.y, bq.z, bq.w};
            bf16x8 fh, fl;
            #pragma unroll
            for (int k = 0; k < 8; ++k) {
                unsigned short h = bf16_rne(wv[k]);
                float hf = __uint_as_float((unsigned)h << 16);
                fh[k] = (short)h; fl[k] = (short)bf16_rne(wv[k] - hf);
            }
            Bd_h[tid] = fh; Bd_l[tid] = fl;
        }
        __syncthreads();

        // ---- MFMA phase: bf16x3 = Ah*Bh + Al*Bh + Ah*Bl
        bf16x8 axh = Axc_h[w][l], axl = Axc_l[w][l];
        bf16x8 arh = Axr_h[w][l], arl = Axr_l[w][l];
        #pragma unroll
        for (int nt = 0; nt < 4; ++nt) {
            bf16x8 bh = Bw_h[nt][l], bl = Bw_l[nt][l];
            accP[nt] = __builtin_amdgcn_mfma_f32_16x16x32_bf16(axh, bh, accP[nt], 0, 0, 0);
            accP[nt] = __builtin_amdgcn_mfma_f32_16x16x32_bf16(axl, bh, accP[nt], 0, 0, 0);
            accP[nt] = __builtin_amdgcn_mfma_f32_16x16x32_bf16(axh, bl, accP[nt], 0, 0, 0);
        }
        {
            bf16x8 bh = Bd_h[l], bl = Bd_l[l];
            accG = __builtin_amdgcn_mfma_f32_16x16x32_bf16(arh, bh, accG, 0, 0, 0);
            accG = __builtin_amdgcn_mfma_f32_16x16x32_bf16(arl, bh, accG, 0, 0, 0);
            accG = __builtin_amdgcn_mfma_f32_16x16x32_bf16(arh, bl, accG, 0, 0, 0);
        }
    }

    // ---- epilogue: As = tanh(G + dt_b); Dl = As @ tr_w.T; write P, Dl
    __syncthreads();
    #pragma unroll
    for (int i = 0; i < 4; ++i)
        AsS[16 * w + 4 * (l >> 4) + i][l & 15] = tanhf(accG[i] + dt_b[l & 15]);
    __syncthreads();

    float as_[4][16];
    #pragma unroll
    for (int i = 0; i < 4; ++i) {
        int mrow = 16 * w + 4 * (l >> 4) + i;        // 0..63
        #pragma unroll
        for (int j = 0; j < 4; ++j) {
            float4 q = *(const float4*)&AsS[mrow][4 * j];
            as_[i][4*j] = q.x; as_[i][4*j+1] = q.y;
            as_[i][4*j+2] = q.z; as_[i][4*j+3] = q.w;
        }
    }
    #pragma unroll
    for (int nt = 0; nt < 4; ++nt) {
        int n = 16 * nt + (l & 15);
        float tw[16];
        #pragma unroll
        for (int j = 0; j < 4; ++j) {
            float4 q = *(const float4*)&trS[n][4 * j];
            tw[4*j] = q.x; tw[4*j+1] = q.y; tw[4*j+2] = q.z; tw[4*j+3] = q.w;
        }
        float ib = in_b[n];
        #pragma unroll
        for (int i = 0; i < 4; ++i) {
            int mrow = 16 * w + 4 * (l >> 4) + i;
            float dlv = 0.f;
            #pragma unroll
            for (int r = 0; r < 16; ++r) dlv = fmaf(as_[i][r], tw[r], dlv);
            // transposed write: row = t0 + n, col = mrow (block owns full tile)
            size_t a = ((size_t)(b * Tn + t0 + n)) * Dn + mrow;
            O[a]      = accP[nt][i] + ib;
            O[a + 64] = dlv;
        }
    }
}

// ---------------------------------------------------------------------------
// Kernel 2: sequential scan (round-4 structure + overhead hiding).
// grid (B), block 64 (1 wave). Lane n owns chain n.
// Changes vs round-4 (118us): (a) ds_reads split 8+8 with counted lgkmcnt(8)
// so the second half's LDS latency hides under quads 0-3's chain; (b) DMA
// issue + S-flush moved INTO the compute region so the compiler schedules
// them into chain-latency shadows; (c) WAITV counts re-derived for new order.
//
// vmcnt ledger (robust to any intra-iteration interleave of flush/issue,
// since counts only use "everything in the previous iteration's region"):
//   chunk c region: [flush S_{c-1}(8) + issue L_{c+2}(16), any order]
//   prologue: L0,L1 -> WAITV(16) drains L0
//   c=1: newer-than-L1 = L2(16)            -> WAITV(16)
//   c in 2..126: newer-than-L_c = S_{c-2}(8)+L_{c+1}(16) = 24 -> WAITV(24)
//   c=127: certainly-newer-than-L127 = S125(8)           -> WAITV(8)
// ---------------------------------------------------------------------------

typedef const __attribute__((address_space(1))) void GVoid;
typedef __attribute__((address_space(3))) void LVoid;
typedef __attribute__((address_space(3))) float LdsFloat;

#define WAITV(N) do {                                                    \
    asm volatile("s_waitcnt vmcnt(" #N ")" ::: "memory");                \
    __builtin_amdgcn_sched_barrier(0);                                   \
} while (0)

// Issue one chunk: 16 x (64 lanes x 16B). LDS dst uniform; HW adds lane*16.
// LDS per buffer: P segs j=0..7 at byte j*1024; Dl segs at 8192 + j*1024.
__device__ __forceinline__ void issue_chunk(float* lds, const float* rp)
{
    #pragma unroll
    for (int j = 0; j < 8; ++j)
        __builtin_amdgcn_global_load_lds((GVoid*)(rp + 4 * j),
                                         (LVoid*)(lds + j * 256), 16, 0, 0);
    #pragma unroll
    for (int j = 0; j < 8; ++j)
        __builtin_amdgcn_global_load_lds((GVoid*)(rp + 64 + 4 * j),
                                         (LVoid*)(lds + (8 + j) * 256), 16, 0, 0);
}

// One chunk: flush prev S, read P/Dl (8+8 with counted lgkm), compute 32
// steps, issue next-next chunk's DMA mid-compute. All DS ops in asm so the
// compiler cannot insert conservative vmcnt drains (round-3 lesson).
__device__ __forceinline__ void chunk_body(const float* buf, int n, float& st,
                                           f32x4 (&sv)[8], float* flush_dst,
                                           float* issue_lds, const float* issue_rp)
{
    const float L2E = 1.44269504088896340736f;
    unsigned a = (unsigned)(unsigned long long)(LdsFloat*)buf
               + (unsigned)(n * 16);
    f32x4 pr[8], dr[8];
    // R_A: quads 0-3 (P + Dl), no wait
    asm volatile(
        "ds_read_b128 %0, %8 offset:0\n\t"
        "ds_read_b128 %1, %8 offset:1024\n\t"
        "ds_read_b128 %2, %8 offset:2048\n\t"
        "ds_read_b128 %3, %8 offset:3072\n\t"
        "ds_read_b128 %4, %8 offset:8192\n\t"
        "ds_read_b128 %5, %8 offset:9216\n\t"
        "ds_read_b128 %6, %8 offset:10240\n\t"
        "ds_read_b128 %7, %8 offset:11264"
        : "=&v"(pr[0]), "=&v"(pr[1]), "=&v"(pr[2]), "=&v"(pr[3]),
          "=&v"(dr[0]), "=&v"(dr[1]), "=&v"(dr[2]), "=&v"(dr[3])
        : "v"(a));
    // R_B: quads 4-7 + wait for R_A only (keep R_B's 8 in flight)
    asm volatile(
        "ds_read_b128 %0, %8 offset:4096\n\t"
        "ds_read_b128 %1, %8 offset:5120\n\t"
        "ds_read_b128 %2, %8 offset:6144\n\t"
        "ds_read_b128 %3, %8 offset:7168\n\t"
        "ds_read_b128 %4, %8 offset:12288\n\t"
        "ds_read_b128 %5, %8 offset:13312\n\t"
        "ds_read_b128 %6, %8 offset:14336\n\t"
        "ds_read_b128 %7, %8 offset:15360\n\t"
        "s_waitcnt lgkmcnt(8)"
        : "=&v"(pr[4]), "=&v"(pr[5]), "=&v"(pr[6]), "=&v"(pr[7]),
          "=&v"(dr[4]), "=&v"(dr[5]), "=&v"(dr[6]), "=&v"(dr[7])
        : "v"(a));
    __builtin_amdgcn_sched_barrier(0);

    // flush previous chunk's S from regs (compiler interleaves into compute)
    if (flush_dst) {
        #pragma unroll
        for (int j = 0; j < 8; ++j)
            *(f32x4*)(flush_dst + 4 * j) = sv[j];
    }

    #define COMPQ(j) do {                                                 \
        _Pragma("unroll")                                                 \
        for (int i = 0; i < 4; ++i) {                                     \
            float d = dr[j][i];                                           \
            float u = st + d;                                             \
            float e = __builtin_amdgcn_exp2f(fmaf(st, -L2E, -d * L2E));   \
            float r = __builtin_amdgcn_rcpf(1.f + e);                     \
            st = fmaf(u, r, pr[j][i]);                                    \
            sv[j][i] = st;                                                \
        }                                                                 \
    } while (0)

    COMPQ(0); COMPQ(1);
    if (issue_lds) issue_chunk(issue_lds, issue_rp);   // hidden in chain shadow
    COMPQ(2); COMPQ(3);
    asm volatile("s_waitcnt lgkmcnt(0)" ::: "memory");
    __builtin_amdgcn_sched_barrier(0);
    COMPQ(4); COMPQ(5); COMPQ(6); COMPQ(7);
    #undef COMPQ
}

#define RP(c) (obase + (size_t)((((c) >> 1) * 64) + n) * Dn + ((c) & 1) * 32)
#define SP(c) (RP(c) + 128)

__global__ __launch_bounds__(64, 1)
void scan_kernel(float* __restrict__ O)
{
    __shared__ __align__(16) float buf[3][4096];   // 3 x 16KB

    const int b = blockIdx.x;
    const int n = threadIdx.x;
    float* obase = O + (size_t)b * Tn * Dn;

    float* b0 = buf[0];   // holds chunk c (read target)
    float* b1 = buf[1];   // holds chunk c+1
    float* b2 = buf[2];   // issue target (chunk c+2)

    f32x4 sv[8];
    float st = 0.f;

    // ---- prologue: chunks 0,1 in flight; chunk 0 issues L2 mid-compute
    issue_chunk(b0, RP(0));                        // L0
    issue_chunk(b1, RP(1));                        // L1
    WAITV(16);                                     // drain L0, keep L1
    chunk_body(b0, n, st, sv, nullptr, b2, RP(2)); // c0 -> sv=S0, issues L2
    { float* t = b0; b0 = b1; b1 = b2; b2 = t; }

    // ---- c = 1 (peeled: only L2 newer than L1)
    WAITV(16);
    chunk_body(b0, n, st, sv, SP(0), b2, RP(3));   // c1, flush S0, issue L3
    { float* t = b0; b0 = b1; b1 = b2; b2 = t; }

    // ---- steady state: c = 2..125 (issue L_{c+2})
    #pragma unroll 1
    for (int c = 2; c <= 125; ++c) {
        WAITV(24);                                 // drain L_c
        chunk_body(b0, n, st, sv, SP(c - 1), b2, RP(c + 2));
        { float* t = b0; b0 = b1; b1 = b2; b2 = t; }
    }

    // ---- c = 126: no issue
    WAITV(24);
    chunk_body(b0, n, st, sv, SP(125), nullptr, nullptr);
    { float* t = b0; b0 = b1; b1 = b2; b2 = t; }

    // ---- c = 127: worst-case newer set = S125(8)
    WAITV(8);
    chunk_body(b0, n, st, sv, SP(126), nullptr, nullptr);

    // final flush S127
    {
        float* sp = SP(127);
        #pragma unroll
        for (int j = 0; j < 8; ++j)
            *(f32x4*)(sp + 4 * j) = sv[j];
    }
}

#undef RP
#undef SP

// ---------------------------------------------------------------------------
// Kernel 3: output projection, in-place. grid (BT/64), block 256.
// (round-4 verified version, v1 transposed-S reader)
// ---------------------------------------------------------------------------
__global__ __launch_bounds__(256)
void out_kernel(const float* __restrict__ out_w, const float* __restrict__ out_b,
                float* __restrict__ O)
{
    __shared__ float Ss[64][Nn + 4];   // Ss[t_local][n]
    __shared__ float wT[Nn][64 + 4];

    const int tid = threadIdx.x;
    const int r0  = blockIdx.x * 64;
    const int c   = tid & 15;
    const int g   = tid >> 4;

    // stage S: element (t = r0+tl, n) lives at O[(r0+n)*Dn + 128 + tl]
    for (int idx = tid; idx < 64 * 16; idx += 256) {
        int nn = idx >> 4, tg = idx & 15;
        float4 v = *(const float4*)&O[(size_t)(r0 + nn) * Dn + 128 + 4 * tg];
        Ss[4 * tg + 0][nn] = v.x;
        Ss[4 * tg + 1][nn] = v.y;
        Ss[4 * tg + 2][nn] = v.z;
        Ss[4 * tg + 3][nn] = v.w;
    }
    __syncthreads();

    for (int cb = 0; cb < Dn / 64; ++cb) {
        const int d0 = cb * 64;
        for (int idx = tid; idx < Nn * 64 / 4; idx += 256) {
            int dl = idx >> 4, n4 = (idx & 15) * 4;
            float4 wv = *(const float4*)&out_w[(size_t)(d0 + dl) * Nn + n4];
            wT[n4 + 0][dl] = wv.x;
            wT[n4 + 1][dl] = wv.y;
            wT[n4 + 2][dl] = wv.z;
            wT[n4 + 3][dl] = wv.w;
        }
        __syncthreads();

        float acc[4][4] = {};
        #pragma unroll
        for (int kq = 0; kq < Nn; kq += 4) {
            float4 wv0 = *(const float4*)&wT[kq + 0][4 * c];
            float4 wv1 = *(const float4*)&wT[kq + 1][4 * c];
            float4 wv2 = *(const float4*)&wT[kq + 2][4 * c];
            float4 wv3 = *(const float4*)&wT[kq + 3][4 * c];
            #pragma unroll
            for (int i = 0; i < 4; ++i) {
                int row = g + 16 * i;
                float4 xv = *(const float4*)&Ss[row][kq];
                acc[i][0] = fmaf(xv.x, wv0.x, fmaf(xv.y, wv1.x, fmaf(xv.z, wv2.x, fmaf(xv.w, wv3.x, acc[i][0]))));
                acc[i][1] = fmaf(xv.x, wv0.y, fmaf(xv.y, wv1.y, fmaf(xv.z, wv2.y, fmaf(xv.w, wv3.y, acc[i][1]))));
                acc[i][2] = fmaf(xv.x, wv0.z, fmaf(xv.y, wv1.z, fmaf(xv.z, wv2.z, fmaf(xv.w, wv3.z, acc[i][2]))));
                acc[i][3] = fmaf(xv.x, wv0.w, fmaf(xv.y, wv1.w, fmaf(xv.z, wv2.w, fmaf(xv.w, wv3.w, acc[i][3]))));
            }
        }

        float4 bb = *(const float4*)&out_b[d0 + 4 * c];
        #pragma unroll
        for (int i = 0; i < 4; ++i) {
            int row = g + 16 * i;
            float4 o = make_float4(acc[i][0] + bb.x, acc[i][1] + bb.y,
                                   acc[i][2] + bb.z, acc[i][3] + bb.w);
            *(float4*)&O[(size_t)(r0 + row) * Dn + d0 + 4 * c] = o;
        }
        __syncthreads();
    }
}

extern "C" void kernel_launch(void* const* d_in, const int* in_sizes, int n_in,
                              void* d_out, int out_size, void* d_ws, size_t ws_size,
                              hipStream_t stream)
{
    const float* x      = (const float*)d_in[0];
    const float* conv_w = (const float*)d_in[1];
    const float* in_w   = (const float*)d_in[2];
    const float* in_b   = (const float*)d_in[3];
    const float* dt_w   = (const float*)d_in[4];
    const float* dt_b   = (const float*)d_in[5];
    const float* tr_w   = (const float*)d_in[6];
    const float* out_w  = (const float*)d_in[7];
    const float* out_b  = (const float*)d_in[8];
    float* O = (float*)d_out;
    (void)d_ws; (void)ws_size;

    dim3 g1(Tn / TT2, Bn);
    prep_kernel<<<g1, 256, 0, stream>>>(x, conv_w, in_w, in_b, dt_w, dt_b, tr_w, O);

    scan_kernel<<<dim3(Bn), 64, 0, stream>>>(O);

    out_kernel<<<dim3((Bn * Tn) / 64), 256, 0, stream>>>(out_w, out_b, O);
}

// Round 7
// 383.555 us; speedup vs baseline: 1.0750x; 1.0606x over previous
//
#include <hip/hip_runtime.h>
#include <math.h>

#define Bn 4
#define Tn 4096
#define Dn 1024
#define Nn 64
#define Rn 16
#define KCONV 4

#define TT2 64    // t-rows per prep block (64-row tiles, 4 waves)
#define KCH 32    // K-chunk (one 16x16x32 MFMA K-step)
#define SU 32     // scan chunk (steps per prefetch block)

typedef __attribute__((ext_vector_type(8))) short bf16x8;
typedef __attribute__((ext_vector_type(4))) float f32x4;

__device__ __forceinline__ unsigned short bf16_rne(float f) {
    unsigned int u = __float_as_uint(f);
    unsigned int r = (u + 0x7fffu + ((u >> 16) & 1u)) >> 16;
    return (unsigned short)r;
}

// Layout v1 (round-4 verified): intermediates live INSIDE d_out, TRANSPOSED
// per 64-row tile. For tile t0' = t & ~63:
//   element (t, n) of P  -> O[(b*Tn + t0' + n)*Dn +   0 + (t - t0')]
//   element (t, n) of Dl -> O[(b*Tn + t0' + n)*Dn +  64 + (t - t0')]
//   element (t, n) of S  -> O[(b*Tn + t0' + n)*Dn + 128 + (t - t0')]
// out_kernel only touches its own 64 rows before overwriting them.

// ---------------------------------------------------------------------------
// Kernel 1 (MFMA bf16x3): fused conv + input proj + delta path.
// Round-7 change: COALESCED staging. x tile goes to LDS with 4 threads/row
// (2 lines/row vs 64-line gathers); A-fragments computed from LDS; B/dt
// staging remapped (n,s)=(tid>>2,tid&3) for 128B-contiguous loads. Fragment
// layout, MFMA phase, and epilogue are byte-identical to the verified code.
// ---------------------------------------------------------------------------
__global__ __launch_bounds__(256)
void prep_kernel(const float* __restrict__ x, const float* __restrict__ conv_w,
                 const float* __restrict__ in_w, const float* __restrict__ in_b,
                 const float* __restrict__ dt_w, const float* __restrict__ dt_b,
                 const float* __restrict__ tr_w,
                 float* __restrict__ O)
{
    __shared__ bf16x8 Axc_h[4][64], Axc_l[4][64];   // A = x+conv (hi/lo), 4 M-tiles
    __shared__ bf16x8 Axr_h[4][64], Axr_l[4][64];   // A = raw x  (hi/lo)
    __shared__ bf16x8 Bw_h[4][64],  Bw_l[4][64];    // B = in_w rows (hi/lo)
    __shared__ bf16x8 Bd_h[64],     Bd_l[64];       // B = dt_w rows (hi/lo)
    __shared__ float  xs[67][36];                   // raw x tile + conv halo (pad 36: 16B-aligned rows, 2-way banks)
    __shared__ float4 cws[32];                      // conv_w[k0..k0+31][0..3]
    __shared__ float  AsS[TT2][17];                 // tanh activations
    __shared__ float  trS[Nn][17];                  // tr_w padded

    const int tid = threadIdx.x;
    const int b   = blockIdx.y;
    const int t0  = blockIdx.x * TT2;               // 64-aligned
    const int l   = tid & 63;
    const int w   = tid >> 6;                       // wave 0..3

    const float* xb = x + (size_t)b * Tn * Dn;

    for (int idx = tid; idx < Nn * Rn; idx += 256)
        trS[idx >> 4][idx & 15] = tr_w[idx];

    const f32x4 z4 = {0.f, 0.f, 0.f, 0.f};
    f32x4 accP[4] = {z4, z4, z4, z4};
    f32x4 accG = z4;

    for (int kc = 0; kc < Dn / KCH; ++kc) {
        const int k0 = kc * KCH;
        __syncthreads();   // B1: prev iter's reads of xs/frags done

        // ---- stage raw x tile: rows 0..66 <-> t = t0-3 .. t0+63, coalesced
        {
            const int row  = tid >> 2;              // 0..63
            const int colg = tid & 3;               // 8-float column group
            const int tp   = t0 - 3 + row;
            float4 a = {0.f,0.f,0.f,0.f}, bq = {0.f,0.f,0.f,0.f};
            if (tp >= 0) {
                const float* src = &xb[(size_t)tp * Dn + k0 + 8 * colg];
                a  = *(const float4*)src;
                bq = *(const float4*)(src + 4);
            }
            *(float4*)&xs[row][8 * colg]     = a;
            *(float4*)&xs[row][8 * colg + 4] = bq;
            if (tid < 12) {                         // rows 64..66 (t0+61..t0+63)
                const int row2 = 64 + (tid >> 2), colg2 = tid & 3;
                const float* s2 = &xb[(size_t)(t0 - 3 + row2) * Dn + k0 + 8 * colg2];
                *(float4*)&xs[row2][8 * colg2]     = *(const float4*)s2;
                *(float4*)&xs[row2][8 * colg2 + 4] = *(const float4*)(s2 + 4);
            }
            if (tid >= 64 && tid < 96)
                cws[tid - 64] = *(const float4*)&conv_w[(size_t)(k0 + tid - 64) * 4];
        }
        // ---- stage B fragments, coalesced remap: n = tid>>2, s = tid&3
        {
            const int n = tid >> 2, s = tid & 3;
            const float* wp = &in_w[(size_t)n * Dn + k0 + 8 * s];
            float4 a  = *(const float4*)wp;
            float4 bq = *(const float4*)(wp + 4);
            float wv[8] = {a.x, a.y, a.z, a.w, bq.x, bq.y, bq.z, bq.w};
            bf16x8 fh, fl;
            #pragma unroll
            for (int k = 0; k < 8; ++k) {
                unsigned short h = bf16_rne(wv[k]);
                float hf = __uint_as_float((unsigned)h << 16);
                fh[k] = (short)h; fl[k] = (short)bf16_rne(wv[k] - hf);
            }
            Bw_h[n >> 4][(n & 15) | (s << 4)] = fh;
            Bw_l[n >> 4][(n & 15) | (s << 4)] = fl;
        }
        if (tid < 64) {
            const int r = tid >> 2, s = tid & 3;
            const float* wp = &dt_w[(size_t)r * Dn + k0 + 8 * s];
            float4 a  = *(const float4*)wp;
            float4 bq = *(const float4*)(wp + 4);
            float wv[8] = {a.x, a.y, a.z, a.w, bq.x, bq.y, bq.z, bq.w};
            bf16x8 fh, fl;
            #pragma unroll
            for (int k = 0; k < 8; ++k) {
                unsigned short h = bf16_rne(wv[k]);
                float hf = __uint_as_float((unsigned)h << 16);
                fh[k] = (short)h; fl[k] = (short)bf16_rne(wv[k] - hf);
            }
            Bd_h[r | (s << 4)] = fh; Bd_l[r | (s << 4)] = fl;
        }
        __syncthreads();   // B2: xs/cws staged

        // ---- A fragments from LDS-staged x: conv + hi/lo split (same slots)
        {
            const int m = tid & 63;                 // output t-row in tile
            const int s = tid >> 6;                 // K-group of 8
            float v[4][8];
            #pragma unroll
            for (int dr = 0; dr < 4; ++dr) {        // xs rows m..m+3 = t-3+dr
                float4 a  = *(const float4*)&xs[m + dr][8 * s];
                float4 bq = *(const float4*)&xs[m + dr][8 * s + 4];
                v[dr][0]=a.x;  v[dr][1]=a.y;  v[dr][2]=a.z;  v[dr][3]=a.w;
                v[dr][4]=bq.x; v[dr][5]=bq.y; v[dr][6]=bq.z; v[dr][7]=bq.w;
            }
            bf16x8 fch, fcl, frh, frl;
            #pragma unroll
            for (int k = 0; k < 8; ++k) {
                float4 cw = cws[8 * s + k];
                float xr = v[3][k];
                float xc = xr;
                xc = fmaf(v[0][k], cw.x, xc);
                xc = fmaf(v[1][k], cw.y, xc);
                xc = fmaf(v[2][k], cw.z, xc);
                xc = fmaf(v[3][k], cw.w, xc);
                unsigned short h; float hf;
                h = bf16_rne(xc); hf = __uint_as_float((unsigned)h << 16);
                fch[k] = (short)h; fcl[k] = (short)bf16_rne(xc - hf);
                h = bf16_rne(xr); hf = __uint_as_float((unsigned)h << 16);
                frh[k] = (short)h; frl[k] = (short)bf16_rne(xr - hf);
            }
            const int lane = (m & 15) | (s << 4), mt = m >> 4;
            Axc_h[mt][lane] = fch; Axc_l[mt][lane] = fcl;
            Axr_h[mt][lane] = frh; Axr_l[mt][lane] = frl;
        }
        __syncthreads();   // B3: fragments ready

        // ---- MFMA phase: bf16x3 = Ah*Bh + Al*Bh + Ah*Bl (unchanged)
        bf16x8 axh = Axc_h[w][l], axl = Axc_l[w][l];
        bf16x8 arh = Axr_h[w][l], arl = Axr_l[w][l];
        #pragma unroll
        for (int nt = 0; nt < 4; ++nt) {
            bf16x8 bh = Bw_h[nt][l], bl = Bw_l[nt][l];
            accP[nt] = __builtin_amdgcn_mfma_f32_16x16x32_bf16(axh, bh, accP[nt], 0, 0, 0);
            accP[nt] = __builtin_amdgcn_mfma_f32_16x16x32_bf16(axl, bh, accP[nt], 0, 0, 0);
            accP[nt] = __builtin_amdgcn_mfma_f32_16x16x32_bf16(axh, bl, accP[nt], 0, 0, 0);
        }
        {
            bf16x8 bh = Bd_h[l], bl = Bd_l[l];
            accG = __builtin_amdgcn_mfma_f32_16x16x32_bf16(arh, bh, accG, 0, 0, 0);
            accG = __builtin_amdgcn_mfma_f32_16x16x32_bf16(arl, bh, accG, 0, 0, 0);
            accG = __builtin_amdgcn_mfma_f32_16x16x32_bf16(arh, bl, accG, 0, 0, 0);
        }
    }

    // ---- epilogue: As = tanh(G + dt_b); Dl = As @ tr_w.T; write P, Dl
    __syncthreads();
    #pragma unroll
    for (int i = 0; i < 4; ++i)
        AsS[16 * w + 4 * (l >> 4) + i][l & 15] = tanhf(accG[i] + dt_b[l & 15]);
    __syncthreads();

    float as_[4][16];
    #pragma unroll
    for (int i = 0; i < 4; ++i) {
        int mrow = 16 * w + 4 * (l >> 4) + i;        // 0..63
        #pragma unroll
        for (int j = 0; j < 4; ++j) {
            float4 q = *(const float4*)&AsS[mrow][4 * j];
            as_[i][4*j] = q.x; as_[i][4*j+1] = q.y;
            as_[i][4*j+2] = q.z; as_[i][4*j+3] = q.w;
        }
    }
    #pragma unroll
    for (int nt = 0; nt < 4; ++nt) {
        int n = 16 * nt + (l & 15);
        float tw[16];
        #pragma unroll
        for (int j = 0; j < 4; ++j) {
            float4 q = *(const float4*)&trS[n][4 * j];
            tw[4*j] = q.x; tw[4*j+1] = q.y; tw[4*j+2] = q.z; tw[4*j+3] = q.w;
        }
        float ib = in_b[n];
        #pragma unroll
        for (int i = 0; i < 4; ++i) {
            int mrow = 16 * w + 4 * (l >> 4) + i;
            float dlv = 0.f;
            #pragma unroll
            for (int r = 0; r < 16; ++r) dlv = fmaf(as_[i][r], tw[r], dlv);
            // transposed write: row = t0 + n, col = mrow (block owns full tile)
            size_t a = ((size_t)(b * Tn + t0 + n)) * Dn + mrow;
            O[a]      = accP[nt][i] + ib;
            O[a + 64] = dlv;
        }
    }
}

// ---------------------------------------------------------------------------
// Kernel 2: sequential scan — EXACT round-4 structure (measured 118us).
// grid (B), block 64 (1 wave). Lane n owns chain n. LDS-staged distance-2
// prefetch, all-asm ds_read block (compiler cannot insert vmcnt drains).
//
// vmcnt ledger (in-order; L=16 loads, S=8 stores; iter c: issue L_{c+2} ->
// WAIT -> flush S_{c-1} -> asm-read buf_c -> compute):
//   prologue: [L0 L1 L2] WAIT(32) keeps L1,L2
//   c=1:      [L1 L2 L3] WAIT(32) keeps L2,L3
//   steady c: [L_c S_{c-2} L_{c+1} S_{c-1} L_{c+2}] -> WAIT(40) drains L_c
//   c=126:    [L126 S124 L127 S125] WAIT(24) drains L126
//   c=127:    [L127 S125 S126]      WAIT(16) drains L127
// ---------------------------------------------------------------------------

typedef const __attribute__((address_space(1))) void GVoid;
typedef __attribute__((address_space(3))) void LVoid;
typedef __attribute__((address_space(3))) float LdsFloat;

#define WAITV(N) do {                                                    \
    asm volatile("s_waitcnt vmcnt(" #N ")" ::: "memory");                \
    __builtin_amdgcn_sched_barrier(0);                                   \
} while (0)

// Issue one chunk: 16 x (64 lanes x 16B). LDS dst uniform; HW adds lane*16.
// LDS per buffer: P segs j=0..7 at byte j*1024; Dl segs at 8192 + j*1024.
__device__ __forceinline__ void issue_chunk(float* lds, const float* rp)
{
    #pragma unroll
    for (int j = 0; j < 8; ++j)
        __builtin_amdgcn_global_load_lds((GVoid*)(rp + 4 * j),
                                         (LVoid*)(lds + j * 256), 16, 0, 0);
    #pragma unroll
    for (int j = 0; j < 8; ++j)
        __builtin_amdgcn_global_load_lds((GVoid*)(rp + 64 + 4 * j),
                                         (LVoid*)(lds + (8 + j) * 256), 16, 0, 0);
}

// All 16 ds_read_b128 + lgkmcnt(0) in ONE asm block.
#define DS_READ_ALL(pv, dv, a)                                           \
    asm volatile(                                                        \
        "ds_read_b128 %0, %16 offset:0\n\t"                              \
        "ds_read_b128 %1, %16 offset:1024\n\t"                           \
        "ds_read_b128 %2, %16 offset:2048\n\t"                           \
        "ds_read_b128 %3, %16 offset:3072\n\t"                           \
        "ds_read_b128 %4, %16 offset:4096\n\t"                           \
        "ds_read_b128 %5, %16 offset:5120\n\t"                           \
        "ds_read_b128 %6, %16 offset:6144\n\t"                           \
        "ds_read_b128 %7, %16 offset:7168\n\t"                           \
        "ds_read_b128 %8, %16 offset:8192\n\t"                           \
        "ds_read_b128 %9, %16 offset:9216\n\t"                           \
        "ds_read_b128 %10, %16 offset:10240\n\t"                         \
        "ds_read_b128 %11, %16 offset:11264\n\t"                         \
        "ds_read_b128 %12, %16 offset:12288\n\t"                         \
        "ds_read_b128 %13, %16 offset:13312\n\t"                         \
        "ds_read_b128 %14, %16 offset:14336\n\t"                         \
        "ds_read_b128 %15, %16 offset:15360\n\t"                         \
        "s_waitcnt lgkmcnt(0)"                                           \
        : "=&v"(pv[0]), "=&v"(pv[1]), "=&v"(pv[2]), "=&v"(pv[3]),        \
          "=&v"(pv[4]), "=&v"(pv[5]), "=&v"(pv[6]), "=&v"(pv[7]),        \
          "=&v"(dv[0]), "=&v"(dv[1]), "=&v"(dv[2]), "=&v"(dv[3]),        \
          "=&v"(dv[4]), "=&v"(dv[5]), "=&v"(dv[6]), "=&v"(dv[7])         \
        : "v"(a) : "memory")

// Store prev chunk's S (if sp), then compute 32 steps from LDS into sv/st.
__device__ __forceinline__ void scan_chunk(const float* buf, int n, float& st,
                                           f32x4 (&sv)[8], float* sp)
{
    const float L2E = 1.44269504088896340736f;
    if (sp) {
        #pragma unroll
        for (int j = 0; j < 8; ++j)
            *(f32x4*)(sp + 4 * j) = sv[j];
    }
    unsigned a = (unsigned)(unsigned long long)(LdsFloat*)buf
               + (unsigned)(n * 16);
    f32x4 pv[8], dv[8];
    DS_READ_ALL(pv, dv, a);
    __builtin_amdgcn_sched_barrier(0);
    #pragma unroll
    for (int j = 0; j < 8; ++j) {
        #pragma unroll
        for (int i = 0; i < 4; ++i) {
            float d  = dv[j][i];
            float u  = st + d;                                  // off critical path
            float e  = __builtin_amdgcn_exp2f(fmaf(st, -L2E, -d * L2E));
            float r  = __builtin_amdgcn_rcpf(1.f + e);
            st = fmaf(u, r, pv[j][i]);
            sv[j][i] = st;
        }
    }
}

#define RP(c) (obase + (size_t)((((c) >> 1) * 64) + n) * Dn + ((c) & 1) * 32)
#define SP(c) (RP(c) + 128)

__global__ __launch_bounds__(64, 1)
void scan_kernel(float* __restrict__ O)
{
    __shared__ __align__(16) float buf[3][4096];   // 3 x 16KB

    const int b = blockIdx.x;
    const int n = threadIdx.x;
    float* obase = O + (size_t)b * Tn * Dn;

    float* b0 = buf[0];   // holds chunk c (read target)
    float* b1 = buf[1];   // holds chunk c+1
    float* b2 = buf[2];   // issue target (chunk c+2)

    f32x4 sv[8];
    float st = 0.f;

    // ---- prologue: fill pipe (chunks 0,1,2), compute chunk 0
    issue_chunk(b0, RP(0));                    // L0
    issue_chunk(b1, RP(1));                    // L1
    issue_chunk(b2, RP(2));                    // L2
    WAITV(32);                                 // drain L0
    scan_chunk(b0, n, st, sv, nullptr);        // c0 -> sv = S0
    { float* t = b0; b0 = b1; b1 = b2; b2 = t; }

    // ---- c = 1
    issue_chunk(b2, RP(3));                    // L3
    WAITV(32);                                 // drain L1
    scan_chunk(b0, n, st, sv, SP(0));          // flush S0, compute c1
    { float* t = b0; b0 = b1; b1 = b2; b2 = t; }

    // ---- steady state: c = 2..125
    #pragma unroll 1
    for (int c = 2; c <= 125; ++c) {
        issue_chunk(b2, RP(c + 2));            // L_{c+2}
        WAITV(40);                             // drain L_c
        scan_chunk(b0, n, st, sv, SP(c - 1));  // flush S_{c-1}, compute c
        { float* t = b0; b0 = b1; b1 = b2; b2 = t; }
    }

    // ---- c = 126: no issue
    WAITV(24);                                 // drain L126
    scan_chunk(b0, n, st, sv, SP(125));
    { float* t = b0; b0 = b1; b1 = b2; b2 = t; }

    // ---- c = 127
    WAITV(16);                                 // drain L127
    scan_chunk(b0, n, st, sv, SP(126));

    // final flush S127
    {
        float* sp = SP(127);
        #pragma unroll
        for (int j = 0; j < 8; ++j)
            *(f32x4*)(sp + 4 * j) = sv[j];
    }
}

#undef RP
#undef SP

// ---------------------------------------------------------------------------
// Kernel 3: output projection, in-place. grid (BT/64), block 256.
// (round-4 verified version, v1 transposed-S reader)
// ---------------------------------------------------------------------------
__global__ __launch_bounds__(256)
void out_kernel(const float* __restrict__ out_w, const float* __restrict__ out_b,
                float* __restrict__ O)
{
    __shared__ float Ss[64][Nn + 4];   // Ss[t_local][n]
    __shared__ float wT[Nn][64 + 4];

    const int tid = threadIdx.x;
    const int r0  = blockIdx.x * 64;
    const int c   = tid & 15;
    const int g   = tid >> 4;

    // stage S: element (t = r0+tl, n) lives at O[(r0+n)*Dn + 128 + tl]
    for (int idx = tid; idx < 64 * 16; idx += 256) {
        int nn = idx >> 4, tg = idx & 15;
        float4 v = *(const float4*)&O[(size_t)(r0 + nn) * Dn + 128 + 4 * tg];
        Ss[4 * tg + 0][nn] = v.x;
        Ss[4 * tg + 1][nn] = v.y;
        Ss[4 * tg + 2][nn] = v.z;
        Ss[4 * tg + 3][nn] = v.w;
    }
    __syncthreads();

    for (int cb = 0; cb < Dn / 64; ++cb) {
        const int d0 = cb * 64;
        for (int idx = tid; idx < Nn * 64 / 4; idx += 256) {
            int dl = idx >> 4, n4 = (idx & 15) * 4;
            float4 wv = *(const float4*)&out_w[(size_t)(d0 + dl) * Nn + n4];
            wT[n4 + 0][dl] = wv.x;
            wT[n4 + 1][dl] = wv.y;
            wT[n4 + 2][dl] = wv.z;
            wT[n4 + 3][dl] = wv.w;
        }
        __syncthreads();

        float acc[4][4] = {};
        #pragma unroll
        for (int kq = 0; kq < Nn; kq += 4) {
            float4 wv0 = *(const float4*)&wT[kq + 0][4 * c];
            float4 wv1 = *(const float4*)&wT[kq + 1][4 * c];
            float4 wv2 = *(const float4*)&wT[kq + 2][4 * c];
            float4 wv3 = *(const float4*)&wT[kq + 3][4 * c];
            #pragma unroll
            for (int i = 0; i < 4; ++i) {
                int row = g + 16 * i;
                float4 xv = *(const float4*)&Ss[row][kq];
                acc[i][0] = fmaf(xv.x, wv0.x, fmaf(xv.y, wv1.x, fmaf(xv.z, wv2.x, fmaf(xv.w, wv3.x, acc[i][0]))));
                acc[i][1] = fmaf(xv.x, wv0.y, fmaf(xv.y, wv1.y, fmaf(xv.z, wv2.y, fmaf(xv.w, wv3.y, acc[i][1]))));
                acc[i][2] = fmaf(xv.x, wv0.z, fmaf(xv.y, wv1.z, fmaf(xv.z, wv2.z, fmaf(xv.w, wv3.z, acc[i][2]))));
                acc[i][3] = fmaf(xv.x, wv0.w, fmaf(xv.y, wv1.w, fmaf(xv.z, wv2.w, fmaf(xv.w, wv3.w, acc[i][3]))));
            }
        }

        float4 bb = *(const float4*)&out_b[d0 + 4 * c];
        #pragma unroll
        for (int i = 0; i < 4; ++i) {
            int row = g + 16 * i;
            float4 o = make_float4(acc[i][0] + bb.x, acc[i][1] + bb.y,
                                   acc[i][2] + bb.z, acc[i][3] + bb.w);
            *(float4*)&O[(size_t)(r0 + row) * Dn + d0 + 4 * c] = o;
        }
        __syncthreads();
    }
}

extern "C" void kernel_launch(void* const* d_in, const int* in_sizes, int n_in,
                              void* d_out, int out_size, void* d_ws, size_t ws_size,
                              hipStream_t stream)
{
    const float* x      = (const float*)d_in[0];
    const float* conv_w = (const float*)d_in[1];
    const float* in_w   = (const float*)d_in[2];
    const float* in_b   = (const float*)d_in[3];
    const float* dt_w   = (const float*)d_in[4];
    const float* dt_b   = (const float*)d_in[5];
    const float* tr_w   = (const float*)d_in[6];
    const float* out_w  = (const float*)d_in[7];
    const float* out_b  = (const float*)d_in[8];
    float* O = (float*)d_out;
    (void)d_ws; (void)ws_size;

    dim3 g1(Tn / TT2, Bn);
    prep_kernel<<<g1, 256, 0, stream>>>(x, conv_w, in_w, in_b, dt_w, dt_b, tr_w, O);

    scan_kernel<<<dim3(Bn), 64, 0, stream>>>(O);

    out_kernel<<<dim3((Bn * Tn) / 64), 256, 0, stream>>>(out_w, out_b, O);
}

// Round 8
// 352.932 us; speedup vs baseline: 1.1683x; 1.0868x over previous
//
#include <hip/hip_runtime.h>
#include <math.h>

#define Bn 4
#define Tn 4096
#define Dn 1024
#define Nn 64
#define Rn 16
#define KCONV 4

#define TT2 32    // t-rows per prep block (32-row tiles, 2 waves, 2 blocks/CU)
#define KCH 32    // K-chunk (one 16x16x32 MFMA K-step)
#define SU 32     // scan chunk (steps per prefetch block)

typedef __attribute__((ext_vector_type(8))) short bf16x8;
typedef __attribute__((ext_vector_type(4))) float f32x4;

__device__ __forceinline__ unsigned short bf16_rne(float f) {
    unsigned int u = __float_as_uint(f);
    unsigned int r = (u + 0x7fffu + ((u >> 16) & 1u)) >> 16;
    return (unsigned short)r;
}

// Layout v1 (round-4 verified): intermediates live INSIDE d_out, TRANSPOSED
// per 64-row tile. For tile t0' = t & ~63:
//   element (t, n) of P  -> O[(b*Tn + t0' + n)*Dn +   0 + (t - t0')]
//   element (t, n) of Dl -> O[(b*Tn + t0' + n)*Dn +  64 + (t - t0')]
//   element (t, n) of S  -> O[(b*Tn + t0' + n)*Dn + 128 + (t - t0')]
// out_kernel only touches its own 64 rows before overwriting them.

// ---------------------------------------------------------------------------
// Kernel 1 (MFMA bf16x3): fused conv + input proj + delta path.
// Round-8: 32-row tiles / 128 threads -> grid 512 = 2 blocks/CU, so a second
// resident block overlaps this block's stage/barrier stalls (round-6 PMC:
// VALUBusy 11%, Occupancy 11% at 1 block/CU). Staging stays coalesced
// (round-7 verified); block structure + epilogue are the round-0/4 verified
// 2-wave form.
// ---------------------------------------------------------------------------
__global__ __launch_bounds__(128)
void prep_kernel(const float* __restrict__ x, const float* __restrict__ conv_w,
                 const float* __restrict__ in_w, const float* __restrict__ in_b,
                 const float* __restrict__ dt_w, const float* __restrict__ dt_b,
                 const float* __restrict__ tr_w,
                 float* __restrict__ O)
{
    __shared__ bf16x8 Axc_h[2][64], Axc_l[2][64];   // A = x+conv (hi/lo), 2 M-tiles
    __shared__ bf16x8 Axr_h[2][64], Axr_l[2][64];   // A = raw x  (hi/lo)
    __shared__ bf16x8 Bw_h[4][64],  Bw_l[4][64];    // B = in_w rows (hi/lo)
    __shared__ bf16x8 Bd_h[64],     Bd_l[64];       // B = dt_w rows (hi/lo)
    __shared__ float  xs[35][36];                   // raw x tile + conv halo
    __shared__ float4 cws[32];                      // conv_w[k0..k0+31][0..3]
    __shared__ float  AsS[TT2][17];                 // tanh activations
    __shared__ float  trS[Nn][17];                  // tr_w padded

    const int tid = threadIdx.x;
    const int b   = blockIdx.y;
    const int t0  = blockIdx.x * TT2;               // 0 or 32 mod 64
    const int l   = tid & 63;
    const int w   = tid >> 6;                       // wave 0..1

    const float* xb = x + (size_t)b * Tn * Dn;

    for (int idx = tid; idx < Nn * Rn; idx += 128)
        trS[idx >> 4][idx & 15] = tr_w[idx];

    const f32x4 z4 = {0.f, 0.f, 0.f, 0.f};
    f32x4 accP[4] = {z4, z4, z4, z4};
    f32x4 accG = z4;

    for (int kc = 0; kc < Dn / KCH; ++kc) {
        const int k0 = kc * KCH;
        __syncthreads();   // B1: prev iter's reads of xs/frags done

        // ---- stage raw x tile: rows 0..34 <-> t = t0-3 .. t0+31, coalesced
        {
            const int row  = tid >> 2;              // 0..31
            const int colg = tid & 3;               // 8-float column group
            const int tp   = t0 - 3 + row;
            float4 a = {0.f,0.f,0.f,0.f}, bq = {0.f,0.f,0.f,0.f};
            if (tp >= 0) {
                const float* src = &xb[(size_t)tp * Dn + k0 + 8 * colg];
                a  = *(const float4*)src;
                bq = *(const float4*)(src + 4);
            }
            *(float4*)&xs[row][8 * colg]     = a;
            *(float4*)&xs[row][8 * colg + 4] = bq;
            if (tid < 12) {                         // rows 32..34 (t0+29..t0+31)
                const int row2 = 32 + (tid >> 2), colg2 = tid & 3;
                const float* s2 = &xb[(size_t)(t0 - 3 + row2) * Dn + k0 + 8 * colg2];
                *(float4*)&xs[row2][8 * colg2]     = *(const float4*)s2;
                *(float4*)&xs[row2][8 * colg2 + 4] = *(const float4*)(s2 + 4);
            }
            if (tid >= 64 && tid < 96)
                cws[tid - 64] = *(const float4*)&conv_w[(size_t)(k0 + tid - 64) * 4];
        }
        // ---- stage B fragments, coalesced remap: n = slot>>2, s = slot&3
        #pragma unroll
        for (int rep = 0; rep < 2; ++rep) {
            const int slot = tid + rep * 128;
            const int n = slot >> 2, s = slot & 3;
            const float* wp = &in_w[(size_t)n * Dn + k0 + 8 * s];
            float4 a  = *(const float4*)wp;
            float4 bq = *(const float4*)(wp + 4);
            float wv[8] = {a.x, a.y, a.z, a.w, bq.x, bq.y, bq.z, bq.w};
            bf16x8 fh, fl;
            #pragma unroll
            for (int k = 0; k < 8; ++k) {
                unsigned short h = bf16_rne(wv[k]);
                float hf = __uint_as_float((unsigned)h << 16);
                fh[k] = (short)h; fl[k] = (short)bf16_rne(wv[k] - hf);
            }
            Bw_h[n >> 4][(n & 15) | (s << 4)] = fh;
            Bw_l[n >> 4][(n & 15) | (s << 4)] = fl;
        }
        if (tid < 64) {
            const int r = tid >> 2, s = tid & 3;
            const float* wp = &dt_w[(size_t)r * Dn + k0 + 8 * s];
            float4 a  = *(const float4*)wp;
            float4 bq = *(const float4*)(wp + 4);
            float wv[8] = {a.x, a.y, a.z, a.w, bq.x, bq.y, bq.z, bq.w};
            bf16x8 fh, fl;
            #pragma unroll
            for (int k = 0; k < 8; ++k) {
                unsigned short h = bf16_rne(wv[k]);
                float hf = __uint_as_float((unsigned)h << 16);
                fh[k] = (short)h; fl[k] = (short)bf16_rne(wv[k] - hf);
            }
            Bd_h[r | (s << 4)] = fh; Bd_l[r | (s << 4)] = fl;
        }
        __syncthreads();   // B2: xs/cws staged

        // ---- A fragments from LDS-staged x: conv + hi/lo split
        {
            const int m = tid & 31;                 // output t-row in tile
            const int s = tid >> 5;                 // K-group of 8 (0..3)
            float v[4][8];
            #pragma unroll
            for (int dr = 0; dr < 4; ++dr) {        // xs rows m..m+3 = t-3+dr
                float4 a  = *(const float4*)&xs[m + dr][8 * s];
                float4 bq = *(const float4*)&xs[m + dr][8 * s + 4];
                v[dr][0]=a.x;  v[dr][1]=a.y;  v[dr][2]=a.z;  v[dr][3]=a.w;
                v[dr][4]=bq.x; v[dr][5]=bq.y; v[dr][6]=bq.z; v[dr][7]=bq.w;
            }
            bf16x8 fch, fcl, frh, frl;
            #pragma unroll
            for (int k = 0; k < 8; ++k) {
                float4 cw = cws[8 * s + k];
                float xr = v[3][k];
                float xc = xr;
                xc = fmaf(v[0][k], cw.x, xc);
                xc = fmaf(v[1][k], cw.y, xc);
                xc = fmaf(v[2][k], cw.z, xc);
                xc = fmaf(v[3][k], cw.w, xc);
                unsigned short h; float hf;
                h = bf16_rne(xc); hf = __uint_as_float((unsigned)h << 16);
                fch[k] = (short)h; fcl[k] = (short)bf16_rne(xc - hf);
                h = bf16_rne(xr); hf = __uint_as_float((unsigned)h << 16);
                frh[k] = (short)h; frl[k] = (short)bf16_rne(xr - hf);
            }
            const int lane = (m & 15) | (s << 4), mt = m >> 4;   // mt 0..1
            Axc_h[mt][lane] = fch; Axc_l[mt][lane] = fcl;
            Axr_h[mt][lane] = frh; Axr_l[mt][lane] = frl;
        }
        __syncthreads();   // B3: fragments ready

        // ---- MFMA phase: bf16x3 = Ah*Bh + Al*Bh + Ah*Bl (unchanged)
        bf16x8 axh = Axc_h[w][l], axl = Axc_l[w][l];
        bf16x8 arh = Axr_h[w][l], arl = Axr_l[w][l];
        #pragma unroll
        for (int nt = 0; nt < 4; ++nt) {
            bf16x8 bh = Bw_h[nt][l], bl = Bw_l[nt][l];
            accP[nt] = __builtin_amdgcn_mfma_f32_16x16x32_bf16(axh, bh, accP[nt], 0, 0, 0);
            accP[nt] = __builtin_amdgcn_mfma_f32_16x16x32_bf16(axl, bh, accP[nt], 0, 0, 0);
            accP[nt] = __builtin_amdgcn_mfma_f32_16x16x32_bf16(axh, bl, accP[nt], 0, 0, 0);
        }
        {
            bf16x8 bh = Bd_h[l], bl = Bd_l[l];
            accG = __builtin_amdgcn_mfma_f32_16x16x32_bf16(arh, bh, accG, 0, 0, 0);
            accG = __builtin_amdgcn_mfma_f32_16x16x32_bf16(arl, bh, accG, 0, 0, 0);
            accG = __builtin_amdgcn_mfma_f32_16x16x32_bf16(arh, bl, accG, 0, 0, 0);
        }
    }

    // ---- epilogue (round-0/4 verified): As = tanh(G + dt_b); Dl = As@tr_w.T
    __syncthreads();
    #pragma unroll
    for (int i = 0; i < 4; ++i)
        AsS[16 * w + 4 * (l >> 4) + i][l & 15] = tanhf(accG[i] + dt_b[l & 15]);
    __syncthreads();

    float as_[4][16];
    #pragma unroll
    for (int i = 0; i < 4; ++i) {
        int mrow = 16 * w + 4 * (l >> 4) + i;        // 0..31
        #pragma unroll
        for (int j = 0; j < 4; ++j) {
            float4 q = *(const float4*)&AsS[mrow][4 * j];
            as_[i][4*j] = q.x; as_[i][4*j+1] = q.y;
            as_[i][4*j+2] = q.z; as_[i][4*j+3] = q.w;
        }
    }
    const int tile0 = t0 & ~63;        // 64-aligned tile base
    const int coff  = t0 & 63;         // col offset of this block's 32 rows
    #pragma unroll
    for (int nt = 0; nt < 4; ++nt) {
        int n = 16 * nt + (l & 15);
        float tw[16];
        #pragma unroll
        for (int j = 0; j < 4; ++j) {
            float4 q = *(const float4*)&trS[n][4 * j];
            tw[4*j] = q.x; tw[4*j+1] = q.y; tw[4*j+2] = q.z; tw[4*j+3] = q.w;
        }
        float ib = in_b[n];
        #pragma unroll
        for (int i = 0; i < 4; ++i) {
            int mrow = 16 * w + 4 * (l >> 4) + i;
            float dlv = 0.f;
            #pragma unroll
            for (int r = 0; r < 16; ++r) dlv = fmaf(as_[i][r], tw[r], dlv);
            // transposed write: row = tile0 + n, col = coff + mrow
            size_t a = ((size_t)(b * Tn + tile0 + n)) * Dn + coff + mrow;
            O[a]      = accP[nt][i] + ib;
            O[a + 64] = dlv;
        }
    }
}

// ---------------------------------------------------------------------------
// Kernel 2: sequential scan — EXACT round-4 structure (measured 118us).
// grid (B), block 64 (1 wave). Lane n owns chain n. LDS-staged distance-2
// prefetch, all-asm ds_read block (compiler cannot insert vmcnt drains).
//
// vmcnt ledger (in-order; L=16 loads, S=8 stores; iter c: issue L_{c+2} ->
// WAIT -> flush S_{c-1} -> asm-read buf_c -> compute):
//   prologue: [L0 L1 L2] WAIT(32) keeps L1,L2
//   c=1:      [L1 L2 L3] WAIT(32) keeps L2,L3
//   steady c: [L_c S_{c-2} L_{c+1} S_{c-1} L_{c+2}] -> WAIT(40) drains L_c
//   c=126:    [L126 S124 L127 S125] WAIT(24) drains L126
//   c=127:    [L127 S125 S126]      WAIT(16) drains L127
// ---------------------------------------------------------------------------

typedef const __attribute__((address_space(1))) void GVoid;
typedef __attribute__((address_space(3))) void LVoid;
typedef __attribute__((address_space(3))) float LdsFloat;

#define WAITV(N) do {                                                    \
    asm volatile("s_waitcnt vmcnt(" #N ")" ::: "memory");                \
    __builtin_amdgcn_sched_barrier(0);                                   \
} while (0)

// Issue one chunk: 16 x (64 lanes x 16B). LDS dst uniform; HW adds lane*16.
// LDS per buffer: P segs j=0..7 at byte j*1024; Dl segs at 8192 + j*1024.
__device__ __forceinline__ void issue_chunk(float* lds, const float* rp)
{
    #pragma unroll
    for (int j = 0; j < 8; ++j)
        __builtin_amdgcn_global_load_lds((GVoid*)(rp + 4 * j),
                                         (LVoid*)(lds + j * 256), 16, 0, 0);
    #pragma unroll
    for (int j = 0; j < 8; ++j)
        __builtin_amdgcn_global_load_lds((GVoid*)(rp + 64 + 4 * j),
                                         (LVoid*)(lds + (8 + j) * 256), 16, 0, 0);
}

// All 16 ds_read_b128 + lgkmcnt(0) in ONE asm block.
#define DS_READ_ALL(pv, dv, a)                                           \
    asm volatile(                                                        \
        "ds_read_b128 %0, %16 offset:0\n\t"                              \
        "ds_read_b128 %1, %16 offset:1024\n\t"                           \
        "ds_read_b128 %2, %16 offset:2048\n\t"                           \
        "ds_read_b128 %3, %16 offset:3072\n\t"                           \
        "ds_read_b128 %4, %16 offset:4096\n\t"                           \
        "ds_read_b128 %5, %16 offset:5120\n\t"                           \
        "ds_read_b128 %6, %16 offset:6144\n\t"                           \
        "ds_read_b128 %7, %16 offset:7168\n\t"                           \
        "ds_read_b128 %8, %16 offset:8192\n\t"                           \
        "ds_read_b128 %9, %16 offset:9216\n\t"                           \
        "ds_read_b128 %10, %16 offset:10240\n\t"                         \
        "ds_read_b128 %11, %16 offset:11264\n\t"                         \
        "ds_read_b128 %12, %16 offset:12288\n\t"                         \
        "ds_read_b128 %13, %16 offset:13312\n\t"                         \
        "ds_read_b128 %14, %16 offset:14336\n\t"                         \
        "ds_read_b128 %15, %16 offset:15360\n\t"                         \
        "s_waitcnt lgkmcnt(0)"                                           \
        : "=&v"(pv[0]), "=&v"(pv[1]), "=&v"(pv[2]), "=&v"(pv[3]),        \
          "=&v"(pv[4]), "=&v"(pv[5]), "=&v"(pv[6]), "=&v"(pv[7]),        \
          "=&v"(dv[0]), "=&v"(dv[1]), "=&v"(dv[2]), "=&v"(dv[3]),        \
          "=&v"(dv[4]), "=&v"(dv[5]), "=&v"(dv[6]), "=&v"(dv[7])         \
        : "v"(a) : "memory")

// Store prev chunk's S (if sp), then compute 32 steps from LDS into sv/st.
__device__ __forceinline__ void scan_chunk(const float* buf, int n, float& st,
                                           f32x4 (&sv)[8], float* sp)
{
    const float L2E = 1.44269504088896340736f;
    if (sp) {
        #pragma unroll
        for (int j = 0; j < 8; ++j)
            *(f32x4*)(sp + 4 * j) = sv[j];
    }
    unsigned a = (unsigned)(unsigned long long)(LdsFloat*)buf
               + (unsigned)(n * 16);
    f32x4 pv[8], dv[8];
    DS_READ_ALL(pv, dv, a);
    __builtin_amdgcn_sched_barrier(0);
    #pragma unroll
    for (int j = 0; j < 8; ++j) {
        #pragma unroll
        for (int i = 0; i < 4; ++i) {
            float d  = dv[j][i];
            float u  = st + d;                                  // off critical path
            float e  = __builtin_amdgcn_exp2f(fmaf(st, -L2E, -d * L2E));
            float r  = __builtin_amdgcn_rcpf(1.f + e);
            st = fmaf(u, r, pv[j][i]);
            sv[j][i] = st;
        }
    }
}

#define RP(c) (obase + (size_t)((((c) >> 1) * 64) + n) * Dn + ((c) & 1) * 32)
#define SP(c) (RP(c) + 128)

__global__ __launch_bounds__(64, 1)
void scan_kernel(float* __restrict__ O)
{
    __shared__ __align__(16) float buf[3][4096];   // 3 x 16KB

    const int b = blockIdx.x;
    const int n = threadIdx.x;
    float* obase = O + (size_t)b * Tn * Dn;

    float* b0 = buf[0];   // holds chunk c (read target)
    float* b1 = buf[1];   // holds chunk c+1
    float* b2 = buf[2];   // issue target (chunk c+2)

    f32x4 sv[8];
    float st = 0.f;

    // ---- prologue: fill pipe (chunks 0,1,2), compute chunk 0
    issue_chunk(b0, RP(0));                    // L0
    issue_chunk(b1, RP(1));                    // L1
    issue_chunk(b2, RP(2));                    // L2
    WAITV(32);                                 // drain L0
    scan_chunk(b0, n, st, sv, nullptr);        // c0 -> sv = S0
    { float* t = b0; b0 = b1; b1 = b2; b2 = t; }

    // ---- c = 1
    issue_chunk(b2, RP(3));                    // L3
    WAITV(32);                                 // drain L1
    scan_chunk(b0, n, st, sv, SP(0));          // flush S0, compute c1
    { float* t = b0; b0 = b1; b1 = b2; b2 = t; }

    // ---- steady state: c = 2..125
    #pragma unroll 1
    for (int c = 2; c <= 125; ++c) {
        issue_chunk(b2, RP(c + 2));            // L_{c+2}
        WAITV(40);                             // drain L_c
        scan_chunk(b0, n, st, sv, SP(c - 1));  // flush S_{c-1}, compute c
        { float* t = b0; b0 = b1; b1 = b2; b2 = t; }
    }

    // ---- c = 126: no issue
    WAITV(24);                                 // drain L126
    scan_chunk(b0, n, st, sv, SP(125));
    { float* t = b0; b0 = b1; b1 = b2; b2 = t; }

    // ---- c = 127
    WAITV(16);                                 // drain L127
    scan_chunk(b0, n, st, sv, SP(126));

    // final flush S127
    {
        float* sp = SP(127);
        #pragma unroll
        for (int j = 0; j < 8; ++j)
            *(f32x4*)(sp + 4 * j) = sv[j];
    }
}

#undef RP
#undef SP

// ---------------------------------------------------------------------------
// Kernel 3: output projection, in-place. grid (BT/64), block 256.
// Round-8: T14 reg-staged double-buffer of wT — cb+1's out_w slice is loaded
// into 4 regs/thread during cb's compute, so the global-load latency no
// longer sits exposed between the two barriers of each cb iteration.
// ---------------------------------------------------------------------------
__global__ __launch_bounds__(256)
void out_kernel(const float* __restrict__ out_w, const float* __restrict__ out_b,
                float* __restrict__ O)
{
    __shared__ float Ss[64][Nn + 4];   // Ss[t_local][n]
    __shared__ float wT[Nn][64 + 4];

    const int tid = threadIdx.x;
    const int r0  = blockIdx.x * 64;
    const int c   = tid & 15;
    const int g   = tid >> 4;

    // per-thread wT slots: idx = tid + q*256, dl = idx>>4, n4 = (idx&15)*4
    float4 wreg[4];
    #pragma unroll
    for (int q = 0; q < 4; ++q) {
        int idx = tid + q * 256;
        int dl = idx >> 4, n4 = (idx & 15) * 4;
        wreg[q] = *(const float4*)&out_w[(size_t)dl * Nn + n4];   // cb = 0
    }

    // stage S: element (t = r0+tl, n) lives at O[(r0+n)*Dn + 128 + tl]
    for (int idx = tid; idx < 64 * 16; idx += 256) {
        int nn = idx >> 4, tg = idx & 15;
        float4 v = *(const float4*)&O[(size_t)(r0 + nn) * Dn + 128 + 4 * tg];
        Ss[4 * tg + 0][nn] = v.x;
        Ss[4 * tg + 1][nn] = v.y;
        Ss[4 * tg + 2][nn] = v.z;
        Ss[4 * tg + 3][nn] = v.w;
    }
    __syncthreads();

    for (int cb = 0; cb < Dn / 64; ++cb) {
        // write this cb's wT from regs (latency already paid during prev cb)
        #pragma unroll
        for (int q = 0; q < 4; ++q) {
            int idx = tid + q * 256;
            int dl = idx >> 4, n4 = (idx & 15) * 4;
            wT[n4 + 0][dl] = wreg[q].x;
            wT[n4 + 1][dl] = wreg[q].y;
            wT[n4 + 2][dl] = wreg[q].z;
            wT[n4 + 3][dl] = wreg[q].w;
        }
        // issue next cb's loads; latency hides under this cb's compute
        if (cb + 1 < Dn / 64) {
            const int d0n = (cb + 1) * 64;
            #pragma unroll
            for (int q = 0; q < 4; ++q) {
                int idx = tid + q * 256;
                int dl = idx >> 4, n4 = (idx & 15) * 4;
                wreg[q] = *(const float4*)&out_w[(size_t)(d0n + dl) * Nn + n4];
            }
        }
        __syncthreads();   // wT ready

        const int d0 = cb * 64;
        float acc[4][4] = {};
        #pragma unroll
        for (int kq = 0; kq < Nn; kq += 4) {
            float4 wv0 = *(const float4*)&wT[kq + 0][4 * c];
            float4 wv1 = *(const float4*)&wT[kq + 1][4 * c];
            float4 wv2 = *(const float4*)&wT[kq + 2][4 * c];
            float4 wv3 = *(const float4*)&wT[kq + 3][4 * c];
            #pragma unroll
            for (int i = 0; i < 4; ++i) {
                int row = g + 16 * i;
                float4 xv = *(const float4*)&Ss[row][kq];
                acc[i][0] = fmaf(xv.x, wv0.x, fmaf(xv.y, wv1.x, fmaf(xv.z, wv2.x, fmaf(xv.w, wv3.x, acc[i][0]))));
                acc[i][1] = fmaf(xv.x, wv0.y, fmaf(xv.y, wv1.y, fmaf(xv.z, wv2.y, fmaf(xv.w, wv3.y, acc[i][1]))));
                acc[i][2] = fmaf(xv.x, wv0.z, fmaf(xv.y, wv1.z, fmaf(xv.z, wv2.z, fmaf(xv.w, wv3.z, acc[i][2]))));
                acc[i][3] = fmaf(xv.x, wv0.w, fmaf(xv.y, wv1.w, fmaf(xv.z, wv2.w, fmaf(xv.w, wv3.w, acc[i][3]))));
            }
        }

        float4 bb = *(const float4*)&out_b[d0 + 4 * c];
        #pragma unroll
        for (int i = 0; i < 4; ++i) {
            int row = g + 16 * i;
            float4 o = make_float4(acc[i][0] + bb.x, acc[i][1] + bb.y,
                                   acc[i][2] + bb.z, acc[i][3] + bb.w);
            *(float4*)&O[(size_t)(r0 + row) * Dn + d0 + 4 * c] = o;
        }
        __syncthreads();   // compute done -> wT reusable next iter
    }
}

extern "C" void kernel_launch(void* const* d_in, const int* in_sizes, int n_in,
                              void* d_out, int out_size, void* d_ws, size_t ws_size,
                              hipStream_t stream)
{
    const float* x      = (const float*)d_in[0];
    const float* conv_w = (const float*)d_in[1];
    const float* in_w   = (const float*)d_in[2];
    const float* in_b   = (const float*)d_in[3];
    const float* dt_w   = (const float*)d_in[4];
    const float* dt_b   = (const float*)d_in[5];
    const float* tr_w   = (const float*)d_in[6];
    const float* out_w  = (const float*)d_in[7];
    const float* out_b  = (const float*)d_in[8];
    float* O = (float*)d_out;
    (void)d_ws; (void)ws_size;

    dim3 g1(Tn / TT2, Bn);
    prep_kernel<<<g1, 128, 0, stream>>>(x, conv_w, in_w, in_b, dt_w, dt_b, tr_w, O);

    scan_kernel<<<dim3(Bn), 64, 0, stream>>>(O);

    out_kernel<<<dim3((Bn * Tn) / 64), 256, 0, stream>>>(out_w, out_b, O);
}

// Round 9
// 337.363 us; speedup vs baseline: 1.2222x; 1.0461x over previous
//
#include <hip/hip_runtime.h>
#include <math.h>

#define Bn 4
#define Tn 4096
#define Dn 1024
#define Nn 64
#define Rn 16
#define KCONV 4

#define TT2 32    // t-rows per prep block (32-row tiles, 2 waves, 2 blocks/CU)
#define KCH 32    // K-chunk (one 16x16x32 MFMA K-step)
#define SU 32     // scan chunk (steps per prefetch block)

typedef __attribute__((ext_vector_type(8))) short bf16x8;
typedef __attribute__((ext_vector_type(4))) float f32x4;

__device__ __forceinline__ unsigned short bf16_rne(float f) {
    unsigned int u = __float_as_uint(f);
    unsigned int r = (u + 0x7fffu + ((u >> 16) & 1u)) >> 16;
    return (unsigned short)r;
}

typedef const __attribute__((address_space(1))) void GVoid;
typedef __attribute__((address_space(3))) void LVoid;
typedef __attribute__((address_space(3))) float LdsFloat;

// Layout v1 (round-4 verified): intermediates live INSIDE d_out, TRANSPOSED
// per 64-row tile. For tile t0' = t & ~63:
//   element (t, n) of P  -> O[(b*Tn + t0' + n)*Dn +   0 + (t - t0')]
//   element (t, n) of Dl -> O[(b*Tn + t0' + n)*Dn +  64 + (t - t0')]
//   element (t, n) of S  -> O[(b*Tn + t0' + n)*Dn + 128 + (t - t0')]
// out_kernel only touches its own 64 rows before overwriting them.

// ---------------------------------------------------------------------------
// Kernel 0 (NEW, round 9): one-time bf16 hi/lo split of in_w / dt_w into
// d_ws, laid out in EXACT fragment-DMA order per K-chunk so prep can stage B
// with 10 global_load_lds and zero VALU. Values bit-identical to the old
// per-block split (same bf16_rne math) -> absmax unchanged.
// ws layout per kc (5120 shorts = 10240 B):
//   shorts [   0,2048) : Bw_h slots 0..255   (slot = nt*64+lane)
//   shorts [2048,4096) : Bw_l slots
//   shorts [4096,4608) : Bd_h slots 0..63
//   shorts [4608,5120) : Bd_l slots
// Total: 32 kc * 10240 B = 327,680 B of d_ws.
// ---------------------------------------------------------------------------
__global__ __launch_bounds__(256)
void prep0_kernel(const float* __restrict__ in_w, const float* __restrict__ dt_w,
                  unsigned short* __restrict__ ws)
{
    const int kc  = blockIdx.x;                 // 0..31
    const int k0  = kc * KCH;
    const int tid = threadIdx.x;
    unsigned short* wsb = ws + (size_t)kc * 5120;

    {   // Bw slot = tid: nt = tid>>6, lane = tid&63; n = nt*16+(lane&15), s = lane>>4
        const int lane = tid & 63;
        const int n = (tid >> 6) * 16 + (lane & 15), s = lane >> 4;
        const float* wp = &in_w[(size_t)n * Dn + k0 + 8 * s];
        float4 a  = *(const float4*)wp;
        float4 bq = *(const float4*)(wp + 4);
        float wv[8] = {a.x, a.y, a.z, a.w, bq.x, bq.y, bq.z, bq.w};
        bf16x8 fh, fl;
        #pragma unroll
        for (int k = 0; k < 8; ++k) {
            unsigned short h = bf16_rne(wv[k]);
            float hf = __uint_as_float((unsigned)h << 16);
            fh[k] = (short)h; fl[k] = (short)bf16_rne(wv[k] - hf);
        }
        *(bf16x8*)&wsb[(size_t)tid * 8]        = fh;
        *(bf16x8*)&wsb[2048 + (size_t)tid * 8] = fl;
    }
    if (tid < 64) {   // Bd slot = tid: r = tid&15, s = tid>>4
        const int r = tid & 15, s = tid >> 4;
        const float* wp = &dt_w[(size_t)r * Dn + k0 + 8 * s];
        float4 a  = *(const float4*)wp;
        float4 bq = *(const float4*)(wp + 4);
        float wv[8] = {a.x, a.y, a.z, a.w, bq.x, bq.y, bq.z, bq.w};
        bf16x8 fh, fl;
        #pragma unroll
        for (int k = 0; k < 8; ++k) {
            unsigned short h = bf16_rne(wv[k]);
            float hf = __uint_as_float((unsigned)h << 16);
            fh[k] = (short)h; fl[k] = (short)bf16_rne(wv[k] - hf);
        }
        *(bf16x8*)&wsb[4096 + (size_t)tid * 8] = fh;
        *(bf16x8*)&wsb[4608 + (size_t)tid * 8] = fl;
    }
}

// ---------------------------------------------------------------------------
// Kernel 1 (MFMA bf16x3): fused conv + input proj + delta path.
// Round-9: B-stage replaced by 10 global_load_lds from the prep0-precomputed
// ws (fragment order). Issued right after B1; the compiler's vmcnt(0) drain
// at __syncthreads (B2) guarantees arrival. A-stage / MFMA / epilogue are the
// round-8 verified code.
// ---------------------------------------------------------------------------
__global__ __launch_bounds__(128)
void prep_kernel(const float* __restrict__ x, const float* __restrict__ conv_w,
                 const unsigned short* __restrict__ ws,
                 const float* __restrict__ in_b, const float* __restrict__ dt_b,
                 const float* __restrict__ tr_w,
                 float* __restrict__ O)
{
    __shared__ bf16x8 Axc_h[2][64], Axc_l[2][64];   // A = x+conv (hi/lo), 2 M-tiles
    __shared__ bf16x8 Axr_h[2][64], Axr_l[2][64];   // A = raw x  (hi/lo)
    __shared__ bf16x8 Bst[640];                     // [0,256)Bw_h [256,512)Bw_l [512,576)Bd_h [576,640)Bd_l
    __shared__ float  xs[35][36];                   // raw x tile + conv halo
    __shared__ float4 cws[32];                      // conv_w[k0..k0+31][0..3]
    __shared__ float  AsS[TT2][17];                 // tanh activations
    __shared__ float  trS[Nn][17];                  // tr_w padded

    const int tid = threadIdx.x;
    const int b   = blockIdx.y;
    const int t0  = blockIdx.x * TT2;               // 0 or 32 mod 64
    const int l   = tid & 63;
    const int w   = tid >> 6;                       // wave 0..1

    const float* xb = x + (size_t)b * Tn * Dn;

    for (int idx = tid; idx < Nn * Rn; idx += 128)
        trS[idx >> 4][idx & 15] = tr_w[idx];

    const f32x4 z4 = {0.f, 0.f, 0.f, 0.f};
    f32x4 accP[4] = {z4, z4, z4, z4};
    f32x4 accG = z4;

    for (int kc = 0; kc < Dn / KCH; ++kc) {
        const int k0 = kc * KCH;
        __syncthreads();   // B1: prev iter's reads of xs/Bst/frags done

        // ---- B-stage: 10 x global_load_lds from ws (wave 0 only; lane l
        // receives Bst slot j*64+l, 16B). Zero VALU.
        if (tid < 64) {
            const unsigned short* wsb = ws + (size_t)kc * 5120 + (size_t)l * 8;
            #pragma unroll
            for (int j = 0; j < 10; ++j)
                __builtin_amdgcn_global_load_lds((GVoid*)(wsb + j * 512),
                                                 (LVoid*)(Bst + j * 64), 16, 0, 0);
        }

        // ---- stage raw x tile: rows 0..34 <-> t = t0-3 .. t0+31, coalesced
        {
            const int row  = tid >> 2;              // 0..31
            const int colg = tid & 3;               // 8-float column group
            const int tp   = t0 - 3 + row;
            float4 a = {0.f,0.f,0.f,0.f}, bq = {0.f,0.f,0.f,0.f};
            if (tp >= 0) {
                const float* src = &xb[(size_t)tp * Dn + k0 + 8 * colg];
                a  = *(const float4*)src;
                bq = *(const float4*)(src + 4);
            }
            *(float4*)&xs[row][8 * colg]     = a;
            *(float4*)&xs[row][8 * colg + 4] = bq;
            if (tid < 12) {                         // rows 32..34 (t0+29..t0+31)
                const int row2 = 32 + (tid >> 2), colg2 = tid & 3;
                const float* s2 = &xb[(size_t)(t0 - 3 + row2) * Dn + k0 + 8 * colg2];
                *(float4*)&xs[row2][8 * colg2]     = *(const float4*)s2;
                *(float4*)&xs[row2][8 * colg2 + 4] = *(const float4*)(s2 + 4);
            }
            if (tid >= 64 && tid < 96)
                cws[tid - 64] = *(const float4*)&conv_w[(size_t)(k0 + tid - 64) * 4];
        }
        __syncthreads();   // B2: xs/cws staged + B-DMA drained (vmcnt(0) at barrier)

        // ---- A fragments from LDS-staged x: conv + hi/lo split
        {
            const int m = tid & 31;                 // output t-row in tile
            const int s = tid >> 5;                 // K-group of 8 (0..3)
            float v[4][8];
            #pragma unroll
            for (int dr = 0; dr < 4; ++dr) {        // xs rows m..m+3 = t-3+dr
                float4 a  = *(const float4*)&xs[m + dr][8 * s];
                float4 bq = *(const float4*)&xs[m + dr][8 * s + 4];
                v[dr][0]=a.x;  v[dr][1]=a.y;  v[dr][2]=a.z;  v[dr][3]=a.w;
                v[dr][4]=bq.x; v[dr][5]=bq.y; v[dr][6]=bq.z; v[dr][7]=bq.w;
            }
            bf16x8 fch, fcl, frh, frl;
            #pragma unroll
            for (int k = 0; k < 8; ++k) {
                float4 cw = cws[8 * s + k];
                float xr = v[3][k];
                float xc = xr;
                xc = fmaf(v[0][k], cw.x, xc);
                xc = fmaf(v[1][k], cw.y, xc);
                xc = fmaf(v[2][k], cw.z, xc);
                xc = fmaf(v[3][k], cw.w, xc);
                unsigned short h; float hf;
                h = bf16_rne(xc); hf = __uint_as_float((unsigned)h << 16);
                fch[k] = (short)h; fcl[k] = (short)bf16_rne(xc - hf);
                h = bf16_rne(xr); hf = __uint_as_float((unsigned)h << 16);
                frh[k] = (short)h; frl[k] = (short)bf16_rne(xr - hf);
            }
            const int lane = (m & 15) | (s << 4), mt = m >> 4;   // mt 0..1
            Axc_h[mt][lane] = fch; Axc_l[mt][lane] = fcl;
            Axr_h[mt][lane] = frh; Axr_l[mt][lane] = frl;
        }
        __syncthreads();   // B3: fragments ready

        // ---- MFMA phase: bf16x3 = Ah*Bh + Al*Bh + Ah*Bl (unchanged math)
        bf16x8 axh = Axc_h[w][l], axl = Axc_l[w][l];
        bf16x8 arh = Axr_h[w][l], arl = Axr_l[w][l];
        #pragma unroll
        for (int nt = 0; nt < 4; ++nt) {
            bf16x8 bh = Bst[nt * 64 + l];
            bf16x8 bl = Bst[256 + nt * 64 + l];
            accP[nt] = __builtin_amdgcn_mfma_f32_16x16x32_bf16(axh, bh, accP[nt], 0, 0, 0);
            accP[nt] = __builtin_amdgcn_mfma_f32_16x16x32_bf16(axl, bh, accP[nt], 0, 0, 0);
            accP[nt] = __builtin_amdgcn_mfma_f32_16x16x32_bf16(axh, bl, accP[nt], 0, 0, 0);
        }
        {
            bf16x8 bh = Bst[512 + l];
            bf16x8 bl = Bst[576 + l];
            accG = __builtin_amdgcn_mfma_f32_16x16x32_bf16(arh, bh, accG, 0, 0, 0);
            accG = __builtin_amdgcn_mfma_f32_16x16x32_bf16(arl, bh, accG, 0, 0, 0);
            accG = __builtin_amdgcn_mfma_f32_16x16x32_bf16(arh, bl, accG, 0, 0, 0);
        }
    }

    // ---- epilogue (verified): As = tanh(G + dt_b); Dl = As@tr_w.T
    __syncthreads();
    #pragma unroll
    for (int i = 0; i < 4; ++i)
        AsS[16 * w + 4 * (l >> 4) + i][l & 15] = tanhf(accG[i] + dt_b[l & 15]);
    __syncthreads();

    float as_[4][16];
    #pragma unroll
    for (int i = 0; i < 4; ++i) {
        int mrow = 16 * w + 4 * (l >> 4) + i;        // 0..31
        #pragma unroll
        for (int j = 0; j < 4; ++j) {
            float4 q = *(const float4*)&AsS[mrow][4 * j];
            as_[i][4*j] = q.x; as_[i][4*j+1] = q.y;
            as_[i][4*j+2] = q.z; as_[i][4*j+3] = q.w;
        }
    }
    const int tile0 = t0 & ~63;        // 64-aligned tile base
    const int coff  = t0 & 63;         // col offset of this block's 32 rows
    #pragma unroll
    for (int nt = 0; nt < 4; ++nt) {
        int n = 16 * nt + (l & 15);
        float tw[16];
        #pragma unroll
        for (int j = 0; j < 4; ++j) {
            float4 q = *(const float4*)&trS[n][4 * j];
            tw[4*j] = q.x; tw[4*j+1] = q.y; tw[4*j+2] = q.z; tw[4*j+3] = q.w;
        }
        float ib = in_b[n];
        #pragma unroll
        for (int i = 0; i < 4; ++i) {
            int mrow = 16 * w + 4 * (l >> 4) + i;
            float dlv = 0.f;
            #pragma unroll
            for (int r = 0; r < 16; ++r) dlv = fmaf(as_[i][r], tw[r], dlv);
            // transposed write: row = tile0 + n, col = coff + mrow
            size_t a = ((size_t)(b * Tn + tile0 + n)) * Dn + coff + mrow;
            O[a]      = accP[nt][i] + ib;
            O[a + 64] = dlv;
        }
    }
}

// ---------------------------------------------------------------------------
// Kernel 2: sequential scan — EXACT round-4 structure (measured ~118us,
// chain-latency-bound: ~57 cyc/step silu dependent chain; frozen).
// grid (B), block 64 (1 wave). Lane n owns chain n. LDS-staged distance-2
// prefetch, all-asm ds_read block (compiler cannot insert vmcnt drains).
//
// vmcnt ledger (in-order; L=16 loads, S=8 stores; iter c: issue L_{c+2} ->
// WAIT -> flush S_{c-1} -> asm-read buf_c -> compute):
//   prologue: [L0 L1 L2] WAIT(32) keeps L1,L2
//   c=1:      [L1 L2 L3] WAIT(32) keeps L2,L3
//   steady c: [L_c S_{c-2} L_{c+1} S_{c-1} L_{c+2}] -> WAIT(40) drains L_c
//   c=126:    [L126 S124 L127 S125] WAIT(24) drains L126
//   c=127:    [L127 S125 S126]      WAIT(16) drains L127
// ---------------------------------------------------------------------------

#define WAITV(N) do {                                                    \
    asm volatile("s_waitcnt vmcnt(" #N ")" ::: "memory");                \
    __builtin_amdgcn_sched_barrier(0);                                   \
} while (0)

// Issue one chunk: 16 x (64 lanes x 16B). LDS dst uniform; HW adds lane*16.
// LDS per buffer: P segs j=0..7 at byte j*1024; Dl segs at 8192 + j*1024.
__device__ __forceinline__ void issue_chunk(float* lds, const float* rp)
{
    #pragma unroll
    for (int j = 0; j < 8; ++j)
        __builtin_amdgcn_global_load_lds((GVoid*)(rp + 4 * j),
                                         (LVoid*)(lds + j * 256), 16, 0, 0);
    #pragma unroll
    for (int j = 0; j < 8; ++j)
        __builtin_amdgcn_global_load_lds((GVoid*)(rp + 64 + 4 * j),
                                         (LVoid*)(lds + (8 + j) * 256), 16, 0, 0);
}

// All 16 ds_read_b128 + lgkmcnt(0) in ONE asm block.
#define DS_READ_ALL(pv, dv, a)                                           \
    asm volatile(                                                        \
        "ds_read_b128 %0, %16 offset:0\n\t"                              \
        "ds_read_b128 %1, %16 offset:1024\n\t"                           \
        "ds_read_b128 %2, %16 offset:2048\n\t"                           \
        "ds_read_b128 %3, %16 offset:3072\n\t"                           \
        "ds_read_b128 %4, %16 offset:4096\n\t"                           \
        "ds_read_b128 %5, %16 offset:5120\n\t"                           \
        "ds_read_b128 %6, %16 offset:6144\n\t"                           \
        "ds_read_b128 %7, %16 offset:7168\n\t"                           \
        "ds_read_b128 %8, %16 offset:8192\n\t"                           \
        "ds_read_b128 %9, %16 offset:9216\n\t"                           \
        "ds_read_b128 %10, %16 offset:10240\n\t"                         \
        "ds_read_b128 %11, %16 offset:11264\n\t"                         \
        "ds_read_b128 %12, %16 offset:12288\n\t"                         \
        "ds_read_b128 %13, %16 offset:13312\n\t"                         \
        "ds_read_b128 %14, %16 offset:14336\n\t"                         \
        "ds_read_b128 %15, %16 offset:15360\n\t"                         \
        "s_waitcnt lgkmcnt(0)"                                           \
        : "=&v"(pv[0]), "=&v"(pv[1]), "=&v"(pv[2]), "=&v"(pv[3]),        \
          "=&v"(pv[4]), "=&v"(pv[5]), "=&v"(pv[6]), "=&v"(pv[7]),        \
          "=&v"(dv[0]), "=&v"(dv[1]), "=&v"(dv[2]), "=&v"(dv[3]),        \
          "=&v"(dv[4]), "=&v"(dv[5]), "=&v"(dv[6]), "=&v"(dv[7])         \
        : "v"(a) : "memory")

// Store prev chunk's S (if sp), then compute 32 steps from LDS into sv/st.
__device__ __forceinline__ void scan_chunk(const float* buf, int n, float& st,
                                           f32x4 (&sv)[8], float* sp)
{
    const float L2E = 1.44269504088896340736f;
    if (sp) {
        #pragma unroll
        for (int j = 0; j < 8; ++j)
            *(f32x4*)(sp + 4 * j) = sv[j];
    }
    unsigned a = (unsigned)(unsigned long long)(LdsFloat*)buf
               + (unsigned)(n * 16);
    f32x4 pv[8], dv[8];
    DS_READ_ALL(pv, dv, a);
    __builtin_amdgcn_sched_barrier(0);
    #pragma unroll
    for (int j = 0; j < 8; ++j) {
        #pragma unroll
        for (int i = 0; i < 4; ++i) {
            float d  = dv[j][i];
            float u  = st + d;                                  // off critical path
            float e  = __builtin_amdgcn_exp2f(fmaf(st, -L2E, -d * L2E));
            float r  = __builtin_amdgcn_rcpf(1.f + e);
            st = fmaf(u, r, pv[j][i]);
            sv[j][i] = st;
        }
    }
}

#define RP(c) (obase + (size_t)((((c) >> 1) * 64) + n) * Dn + ((c) & 1) * 32)
#define SP(c) (RP(c) + 128)

__global__ __launch_bounds__(64, 1)
void scan_kernel(float* __restrict__ O)
{
    __shared__ __align__(16) float buf[3][4096];   // 3 x 16KB

    const int b = blockIdx.x;
    const int n = threadIdx.x;
    float* obase = O + (size_t)b * Tn * Dn;

    float* b0 = buf[0];   // holds chunk c (read target)
    float* b1 = buf[1];   // holds chunk c+1
    float* b2 = buf[2];   // issue target (chunk c+2)

    f32x4 sv[8];
    float st = 0.f;

    // ---- prologue: fill pipe (chunks 0,1,2), compute chunk 0
    issue_chunk(b0, RP(0));                    // L0
    issue_chunk(b1, RP(1));                    // L1
    issue_chunk(b2, RP(2));                    // L2
    WAITV(32);                                 // drain L0
    scan_chunk(b0, n, st, sv, nullptr);        // c0 -> sv = S0
    { float* t = b0; b0 = b1; b1 = b2; b2 = t; }

    // ---- c = 1
    issue_chunk(b2, RP(3));                    // L3
    WAITV(32);                                 // drain L1
    scan_chunk(b0, n, st, sv, SP(0));          // flush S0, compute c1
    { float* t = b0; b0 = b1; b1 = b2; b2 = t; }

    // ---- steady state: c = 2..125
    #pragma unroll 1
    for (int c = 2; c <= 125; ++c) {
        issue_chunk(b2, RP(c + 2));            // L_{c+2}
        WAITV(40);                             // drain L_c
        scan_chunk(b0, n, st, sv, SP(c - 1));  // flush S_{c-1}, compute c
        { float* t = b0; b0 = b1; b1 = b2; b2 = t; }
    }

    // ---- c = 126: no issue
    WAITV(24);                                 // drain L126
    scan_chunk(b0, n, st, sv, SP(125));
    { float* t = b0; b0 = b1; b1 = b2; b2 = t; }

    // ---- c = 127
    WAITV(16);                                 // drain L127
    scan_chunk(b0, n, st, sv, SP(126));

    // final flush S127
    {
        float* sp = SP(127);
        #pragma unroll
        for (int j = 0; j < 8; ++j)
            *(f32x4*)(sp + 4 * j) = sv[j];
    }
}

#undef RP
#undef SP

// ---------------------------------------------------------------------------
// Kernel 3: output projection, in-place. grid (BT/64), block 256.
// Round-8 verified: T14 reg-staged double-buffer of wT (cb+1's out_w slice
// loaded during cb's compute).
// ---------------------------------------------------------------------------
__global__ __launch_bounds__(256)
void out_kernel(const float* __restrict__ out_w, const float* __restrict__ out_b,
                float* __restrict__ O)
{
    __shared__ float Ss[64][Nn + 4];   // Ss[t_local][n]
    __shared__ float wT[Nn][64 + 4];

    const int tid = threadIdx.x;
    const int r0  = blockIdx.x * 64;
    const int c   = tid & 15;
    const int g   = tid >> 4;

    // per-thread wT slots: idx = tid + q*256, dl = idx>>4, n4 = (idx&15)*4
    float4 wreg[4];
    #pragma unroll
    for (int q = 0; q < 4; ++q) {
        int idx = tid + q * 256;
        int dl = idx >> 4, n4 = (idx & 15) * 4;
        wreg[q] = *(const float4*)&out_w[(size_t)dl * Nn + n4];   // cb = 0
    }

    // stage S: element (t = r0+tl, n) lives at O[(r0+n)*Dn + 128 + tl]
    for (int idx = tid; idx < 64 * 16; idx += 256) {
        int nn = idx >> 4, tg = idx & 15;
        float4 v = *(const float4*)&O[(size_t)(r0 + nn) * Dn + 128 + 4 * tg];
        Ss[4 * tg + 0][nn] = v.x;
        Ss[4 * tg + 1][nn] = v.y;
        Ss[4 * tg + 2][nn] = v.z;
        Ss[4 * tg + 3][nn] = v.w;
    }
    __syncthreads();

    for (int cb = 0; cb < Dn / 64; ++cb) {
        // write this cb's wT from regs (latency already paid during prev cb)
        #pragma unroll
        for (int q = 0; q < 4; ++q) {
            int idx = tid + q * 256;
            int dl = idx >> 4, n4 = (idx & 15) * 4;
            wT[n4 + 0][dl] = wreg[q].x;
            wT[n4 + 1][dl] = wreg[q].y;
            wT[n4 + 2][dl] = wreg[q].z;
            wT[n4 + 3][dl] = wreg[q].w;
        }
        // issue next cb's loads; latency hides under this cb's compute
        if (cb + 1 < Dn / 64) {
            const int d0n = (cb + 1) * 64;
            #pragma unroll
            for (int q = 0; q < 4; ++q) {
                int idx = tid + q * 256;
                int dl = idx >> 4, n4 = (idx & 15) * 4;
                wreg[q] = *(const float4*)&out_w[(size_t)(d0n + dl) * Nn + n4];
            }
        }
        __syncthreads();   // wT ready

        const int d0 = cb * 64;
        float acc[4][4] = {};
        #pragma unroll
        for (int kq = 0; kq < Nn; kq += 4) {
            float4 wv0 = *(const float4*)&wT[kq + 0][4 * c];
            float4 wv1 = *(const float4*)&wT[kq + 1][4 * c];
            float4 wv2 = *(const float4*)&wT[kq + 2][4 * c];
            float4 wv3 = *(const float4*)&wT[kq + 3][4 * c];
            #pragma unroll
            for (int i = 0; i < 4; ++i) {
                int row = g + 16 * i;
                float4 xv = *(const float4*)&Ss[row][kq];
                acc[i][0] = fmaf(xv.x, wv0.x, fmaf(xv.y, wv1.x, fmaf(xv.z, wv2.x, fmaf(xv.w, wv3.x, acc[i][0]))));
                acc[i][1] = fmaf(xv.x, wv0.y, fmaf(xv.y, wv1.y, fmaf(xv.z, wv2.y, fmaf(xv.w, wv3.y, acc[i][1]))));
                acc[i][2] = fmaf(xv.x, wv0.z, fmaf(xv.y, wv1.z, fmaf(xv.z, wv2.z, fmaf(xv.w, wv3.z, acc[i][2]))));
                acc[i][3] = fmaf(xv.x, wv0.w, fmaf(xv.y, wv1.w, fmaf(xv.z, wv2.w, fmaf(xv.w, wv3.w, acc[i][3]))));
            }
        }

        float4 bb = *(const float4*)&out_b[d0 + 4 * c];
        #pragma unroll
        for (int i = 0; i < 4; ++i) {
            int row = g + 16 * i;
            float4 o = make_float4(acc[i][0] + bb.x, acc[i][1] + bb.y,
                                   acc[i][2] + bb.z, acc[i][3] + bb.w);
            *(float4*)&O[(size_t)(r0 + row) * Dn + d0 + 4 * c] = o;
        }
        __syncthreads();   // compute done -> wT reusable next iter
    }
}

extern "C" void kernel_launch(void* const* d_in, const int* in_sizes, int n_in,
                              void* d_out, int out_size, void* d_ws, size_t ws_size,
                              hipStream_t stream)
{
    const float* x      = (const float*)d_in[0];
    const float* conv_w = (const float*)d_in[1];
    const float* in_w   = (const float*)d_in[2];
    const float* in_b   = (const float*)d_in[3];
    const float* dt_w   = (const float*)d_in[4];
    const float* dt_b   = (const float*)d_in[5];
    const float* tr_w   = (const float*)d_in[6];
    const float* out_w  = (const float*)d_in[7];
    const float* out_b  = (const float*)d_in[8];
    float* O = (float*)d_out;
    unsigned short* ws = (unsigned short*)d_ws;   // needs 327,680 B
    (void)ws_size;

    prep0_kernel<<<dim3(Dn / KCH), 256, 0, stream>>>(in_w, dt_w, ws);

    dim3 g1(Tn / TT2, Bn);
    prep_kernel<<<g1, 128, 0, stream>>>(x, conv_w, ws, in_b, dt_b, tr_w, O);

    scan_kernel<<<dim3(Bn), 64, 0, stream>>>(O);

    out_kernel<<<dim3((Bn * Tn) / 64), 256, 0, stream>>>(out_w, out_b, O);
}

// Round 10
// 306.745 us; speedup vs baseline: 1.3442x; 1.0998x over previous
//
#include <hip/hip_runtime.h>
#include <math.h>

#define Bn 4
#define Tn 4096
#define Dn 1024
#define Nn 64
#define Rn 16
#define KCONV 4

#define TT2 32    // t-rows per prep block (32-row tiles, 2 waves, 2 blocks/CU)
#define KCH 32    // K-chunk (one 16x16x32 MFMA K-step)
#define SU 32    // scan chunk (steps per prefetch block)

typedef __attribute__((ext_vector_type(8))) short bf16x8;
typedef __attribute__((ext_vector_type(4))) float f32x4;

__device__ __forceinline__ unsigned short bf16_rne(float f) {
    unsigned int u = __float_as_uint(f);
    unsigned int r = (u + 0x7fffu + ((u >> 16) & 1u)) >> 16;
    return (unsigned short)r;
}

typedef const __attribute__((address_space(1))) void GVoid;
typedef __attribute__((address_space(3))) void LVoid;
typedef __attribute__((address_space(3))) float LdsFloat;

// Layout v1 (round-4 verified): intermediates live INSIDE d_out, TRANSPOSED
// per 64-row tile. For tile t0' = t & ~63:
//   element (t, n) of P  -> O[(b*Tn + t0' + n)*Dn +   0 + (t - t0')]
//   element (t, n) of Dl -> O[(b*Tn + t0' + n)*Dn +  64 + (t - t0')]
//   element (t, n) of S  -> O[(b*Tn + t0' + n)*Dn + 128 + (t - t0')]
// out_kernel only touches its own 64 rows before overwriting them.

// ---------------------------------------------------------------------------
// Kernel 0: one-time bf16 hi/lo weight splits into d_ws (needs 589,824 B).
//  blocks 0..31 : in_w/dt_w per-kc fragments (round-9 verified layout)
//  blocks 32..95: out_w fragments for the MFMA out_kernel.
//    ws2 = ws + 163840 shorts; per d-tile dt (0..63), 2048 shorts:
//      [kh(2)][part(2: h,l)][lane(64)][8 shorts]
//    lane = (d&15) | (kgrp<<4) holds out_w[d][kh*32 + kgrp*8 .. +8]  (B-frag
//    convention byte-identical to prep's Bw, which is absmax-verified).
// ---------------------------------------------------------------------------
__global__ __launch_bounds__(256)
void prep0_kernel(const float* __restrict__ in_w, const float* __restrict__ dt_w,
                  const float* __restrict__ out_w, unsigned short* __restrict__ ws)
{
    const int tid = threadIdx.x;
    if (blockIdx.x < 32) {
        const int kc  = blockIdx.x;
        const int k0  = kc * KCH;
        unsigned short* wsb = ws + (size_t)kc * 5120;
        {   // Bw slot = tid: nt = tid>>6, lane = tid&63
            const int lane = tid & 63;
            const int n = (tid >> 6) * 16 + (lane & 15), s = lane >> 4;
            const float* wp = &in_w[(size_t)n * Dn + k0 + 8 * s];
            float4 a  = *(const float4*)wp;
            float4 bq = *(const float4*)(wp + 4);
            float wv[8] = {a.x, a.y, a.z, a.w, bq.x, bq.y, bq.z, bq.w};
            bf16x8 fh, fl;
            #pragma unroll
            for (int k = 0; k < 8; ++k) {
                unsigned short h = bf16_rne(wv[k]);
                float hf = __uint_as_float((unsigned)h << 16);
                fh[k] = (short)h; fl[k] = (short)bf16_rne(wv[k] - hf);
            }
            *(bf16x8*)&wsb[(size_t)tid * 8]        = fh;
            *(bf16x8*)&wsb[2048 + (size_t)tid * 8] = fl;
        }
        if (tid < 64) {   // Bd slot = tid
            const int r = tid & 15, s = tid >> 4;
            const float* wp = &dt_w[(size_t)r * Dn + k0 + 8 * s];
            float4 a  = *(const float4*)wp;
            float4 bq = *(const float4*)(wp + 4);
            float wv[8] = {a.x, a.y, a.z, a.w, bq.x, bq.y, bq.z, bq.w};
            bf16x8 fh, fl;
            #pragma unroll
            for (int k = 0; k < 8; ++k) {
                unsigned short h = bf16_rne(wv[k]);
                float hf = __uint_as_float((unsigned)h << 16);
                fh[k] = (short)h; fl[k] = (short)bf16_rne(wv[k] - hf);
            }
            *(bf16x8*)&wsb[4096 + (size_t)tid * 8] = fh;
            *(bf16x8*)&wsb[4608 + (size_t)tid * 8] = fl;
        }
    } else {
        const int dt = blockIdx.x - 32;            // 0..63
        if (tid < 128) {
            const int kh = tid >> 6, lane = tid & 63;
            const int d  = dt * 16 + (lane & 15);
            const int n0 = kh * 32 + (lane >> 4) * 8;
            const float* wp = &out_w[(size_t)d * Nn + n0];
            float4 a  = *(const float4*)wp;
            float4 bq = *(const float4*)(wp + 4);
            float wv[8] = {a.x, a.y, a.z, a.w, bq.x, bq.y, bq.z, bq.w};
            bf16x8 fh, fl;
            #pragma unroll
            for (int k = 0; k < 8; ++k) {
                unsigned short h = bf16_rne(wv[k]);
                float hf = __uint_as_float((unsigned)h << 16);
                fh[k] = (short)h; fl[k] = (short)bf16_rne(wv[k] - hf);
            }
            unsigned short* wsb = ws + 163840 + (size_t)dt * 2048
                                + (size_t)kh * 1024 + (size_t)lane * 8;
            *(bf16x8*)wsb         = fh;    // part 0 (hi)
            *(bf16x8*)(wsb + 512) = fl;    // part 1 (lo)
        }
    }
}

// ---------------------------------------------------------------------------
// Kernel 1 (MFMA bf16x3): fused conv + input proj + delta path.
// Round-9 verified version (B via 10 global_load_lds from ws), unchanged.
// ---------------------------------------------------------------------------
__global__ __launch_bounds__(128)
void prep_kernel(const float* __restrict__ x, const float* __restrict__ conv_w,
                 const unsigned short* __restrict__ ws,
                 const float* __restrict__ in_b, const float* __restrict__ dt_b,
                 const float* __restrict__ tr_w,
                 float* __restrict__ O)
{
    __shared__ bf16x8 Axc_h[2][64], Axc_l[2][64];   // A = x+conv (hi/lo), 2 M-tiles
    __shared__ bf16x8 Axr_h[2][64], Axr_l[2][64];   // A = raw x  (hi/lo)
    __shared__ bf16x8 Bst[640];                     // [0,256)Bw_h [256,512)Bw_l [512,576)Bd_h [576,640)Bd_l
    __shared__ float  xs[35][36];                   // raw x tile + conv halo
    __shared__ float4 cws[32];                      // conv_w[k0..k0+31][0..3]
    __shared__ float  AsS[TT2][17];                 // tanh activations
    __shared__ float  trS[Nn][17];                  // tr_w padded

    const int tid = threadIdx.x;
    const int b   = blockIdx.y;
    const int t0  = blockIdx.x * TT2;               // 0 or 32 mod 64
    const int l   = tid & 63;
    const int w   = tid >> 6;                       // wave 0..1

    const float* xb = x + (size_t)b * Tn * Dn;

    for (int idx = tid; idx < Nn * Rn; idx += 128)
        trS[idx >> 4][idx & 15] = tr_w[idx];

    const f32x4 z4 = {0.f, 0.f, 0.f, 0.f};
    f32x4 accP[4] = {z4, z4, z4, z4};
    f32x4 accG = z4;

    for (int kc = 0; kc < Dn / KCH; ++kc) {
        const int k0 = kc * KCH;
        __syncthreads();   // B1: prev iter's reads of xs/Bst/frags done

        // ---- B-stage: 10 x global_load_lds from ws (wave 0 only). Zero VALU.
        if (tid < 64) {
            const unsigned short* wsb = ws + (size_t)kc * 5120 + (size_t)l * 8;
            #pragma unroll
            for (int j = 0; j < 10; ++j)
                __builtin_amdgcn_global_load_lds((GVoid*)(wsb + j * 512),
                                                 (LVoid*)(Bst + j * 64), 16, 0, 0);
        }

        // ---- stage raw x tile: rows 0..34 <-> t = t0-3 .. t0+31, coalesced
        {
            const int row  = tid >> 2;              // 0..31
            const int colg = tid & 3;               // 8-float column group
            const int tp   = t0 - 3 + row;
            float4 a = {0.f,0.f,0.f,0.f}, bq = {0.f,0.f,0.f,0.f};
            if (tp >= 0) {
                const float* src = &xb[(size_t)tp * Dn + k0 + 8 * colg];
                a  = *(const float4*)src;
                bq = *(const float4*)(src + 4);
            }
            *(float4*)&xs[row][8 * colg]     = a;
            *(float4*)&xs[row][8 * colg + 4] = bq;
            if (tid < 12) {                         // rows 32..34 (t0+29..t0+31)
                const int row2 = 32 + (tid >> 2), colg2 = tid & 3;
                const float* s2 = &xb[(size_t)(t0 - 3 + row2) * Dn + k0 + 8 * colg2];
                *(float4*)&xs[row2][8 * colg2]     = *(const float4*)s2;
                *(float4*)&xs[row2][8 * colg2 + 4] = *(const float4*)(s2 + 4);
            }
            if (tid >= 64 && tid < 96)
                cws[tid - 64] = *(const float4*)&conv_w[(size_t)(k0 + tid - 64) * 4];
        }
        __syncthreads();   // B2: xs/cws staged + B-DMA drained (vmcnt(0) at barrier)

        // ---- A fragments from LDS-staged x: conv + hi/lo split
        {
            const int m = tid & 31;                 // output t-row in tile
            const int s = tid >> 5;                 // K-group of 8 (0..3)
            float v[4][8];
            #pragma unroll
            for (int dr = 0; dr < 4; ++dr) {        // xs rows m..m+3 = t-3+dr
                float4 a  = *(const float4*)&xs[m + dr][8 * s];
                float4 bq = *(const float4*)&xs[m + dr][8 * s + 4];
                v[dr][0]=a.x;  v[dr][1]=a.y;  v[dr][2]=a.z;  v[dr][3]=a.w;
                v[dr][4]=bq.x; v[dr][5]=bq.y; v[dr][6]=bq.z; v[dr][7]=bq.w;
            }
            bf16x8 fch, fcl, frh, frl;
            #pragma unroll
            for (int k = 0; k < 8; ++k) {
                float4 cw = cws[8 * s + k];
                float xr = v[3][k];
                float xc = xr;
                xc = fmaf(v[0][k], cw.x, xc);
                xc = fmaf(v[1][k], cw.y, xc);
                xc = fmaf(v[2][k], cw.z, xc);
                xc = fmaf(v[3][k], cw.w, xc);
                unsigned short h; float hf;
                h = bf16_rne(xc); hf = __uint_as_float((unsigned)h << 16);
                fch[k] = (short)h; fcl[k] = (short)bf16_rne(xc - hf);
                h = bf16_rne(xr); hf = __uint_as_float((unsigned)h << 16);
                frh[k] = (short)h; frl[k] = (short)bf16_rne(xr - hf);
            }
            const int lane = (m & 15) | (s << 4), mt = m >> 4;   // mt 0..1
            Axc_h[mt][lane] = fch; Axc_l[mt][lane] = fcl;
            Axr_h[mt][lane] = frh; Axr_l[mt][lane] = frl;
        }
        __syncthreads();   // B3: fragments ready

        // ---- MFMA phase: bf16x3 = Ah*Bh + Al*Bh + Ah*Bl
        bf16x8 axh = Axc_h[w][l], axl = Axc_l[w][l];
        bf16x8 arh = Axr_h[w][l], arl = Axr_l[w][l];
        #pragma unroll
        for (int nt = 0; nt < 4; ++nt) {
            bf16x8 bh = Bst[nt * 64 + l];
            bf16x8 bl = Bst[256 + nt * 64 + l];
            accP[nt] = __builtin_amdgcn_mfma_f32_16x16x32_bf16(axh, bh, accP[nt], 0, 0, 0);
            accP[nt] = __builtin_amdgcn_mfma_f32_16x16x32_bf16(axl, bh, accP[nt], 0, 0, 0);
            accP[nt] = __builtin_amdgcn_mfma_f32_16x16x32_bf16(axh, bl, accP[nt], 0, 0, 0);
        }
        {
            bf16x8 bh = Bst[512 + l];
            bf16x8 bl = Bst[576 + l];
            accG = __builtin_amdgcn_mfma_f32_16x16x32_bf16(arh, bh, accG, 0, 0, 0);
            accG = __builtin_amdgcn_mfma_f32_16x16x32_bf16(arl, bh, accG, 0, 0, 0);
            accG = __builtin_amdgcn_mfma_f32_16x16x32_bf16(arh, bl, accG, 0, 0, 0);
        }
    }

    // ---- epilogue (verified): As = tanh(G + dt_b); Dl = As@tr_w.T
    __syncthreads();
    #pragma unroll
    for (int i = 0; i < 4; ++i)
        AsS[16 * w + 4 * (l >> 4) + i][l & 15] = tanhf(accG[i] + dt_b[l & 15]);
    __syncthreads();

    float as_[4][16];
    #pragma unroll
    for (int i = 0; i < 4; ++i) {
        int mrow = 16 * w + 4 * (l >> 4) + i;        // 0..31
        #pragma unroll
        for (int j = 0; j < 4; ++j) {
            float4 q = *(const float4*)&AsS[mrow][4 * j];
            as_[i][4*j] = q.x; as_[i][4*j+1] = q.y;
            as_[i][4*j+2] = q.z; as_[i][4*j+3] = q.w;
        }
    }
    const int tile0 = t0 & ~63;        // 64-aligned tile base
    const int coff  = t0 & 63;         // col offset of this block's 32 rows
    #pragma unroll
    for (int nt = 0; nt < 4; ++nt) {
        int n = 16 * nt + (l & 15);
        float tw[16];
        #pragma unroll
        for (int j = 0; j < 4; ++j) {
            float4 q = *(const float4*)&trS[n][4 * j];
            tw[4*j] = q.x; tw[4*j+1] = q.y; tw[4*j+2] = q.z; tw[4*j+3] = q.w;
        }
        float ib = in_b[n];
        #pragma unroll
        for (int i = 0; i < 4; ++i) {
            int mrow = 16 * w + 4 * (l >> 4) + i;
            float dlv = 0.f;
            #pragma unroll
            for (int r = 0; r < 16; ++r) dlv = fmaf(as_[i][r], tw[r], dlv);
            // transposed write: row = tile0 + n, col = coff + mrow
            size_t a = ((size_t)(b * Tn + tile0 + n)) * Dn + coff + mrow;
            O[a]      = accP[nt][i] + ib;
            O[a + 64] = dlv;
        }
    }
}

// ---------------------------------------------------------------------------
// Kernel 2: sequential scan — EXACT round-4 structure (117.7us, chain-bound;
// frozen). grid (B), block 64. LDS-staged distance-2 prefetch, all-asm reads.
// vmcnt ledger: prologue WAIT(32)x2; steady WAIT(40); tail WAIT(24)/WAIT(16).
// ---------------------------------------------------------------------------

#define WAITV(N) do {                                                    \
    asm volatile("s_waitcnt vmcnt(" #N ")" ::: "memory");                \
    __builtin_amdgcn_sched_barrier(0);                                   \
} while (0)

__device__ __forceinline__ void issue_chunk(float* lds, const float* rp)
{
    #pragma unroll
    for (int j = 0; j < 8; ++j)
        __builtin_amdgcn_global_load_lds((GVoid*)(rp + 4 * j),
                                         (LVoid*)(lds + j * 256), 16, 0, 0);
    #pragma unroll
    for (int j = 0; j < 8; ++j)
        __builtin_amdgcn_global_load_lds((GVoid*)(rp + 64 + 4 * j),
                                         (LVoid*)(lds + (8 + j) * 256), 16, 0, 0);
}

#define DS_READ_ALL(pv, dv, a)                                           \
    asm volatile(                                                        \
        "ds_read_b128 %0, %16 offset:0\n\t"                              \
        "ds_read_b128 %1, %16 offset:1024\n\t"                           \
        "ds_read_b128 %2, %16 offset:2048\n\t"                           \
        "ds_read_b128 %3, %16 offset:3072\n\t"                           \
        "ds_read_b128 %4, %16 offset:4096\n\t"                           \
        "ds_read_b128 %5, %16 offset:5120\n\t"                           \
        "ds_read_b128 %6, %16 offset:6144\n\t"                           \
        "ds_read_b128 %7, %16 offset:7168\n\t"                           \
        "ds_read_b128 %8, %16 offset:8192\n\t"                           \
        "ds_read_b128 %9, %16 offset:9216\n\t"                           \
        "ds_read_b128 %10, %16 offset:10240\n\t"                         \
        "ds_read_b128 %11, %16 offset:11264\n\t"                         \
        "ds_read_b128 %12, %16 offset:12288\n\t"                         \
        "ds_read_b128 %13, %16 offset:13312\n\t"                         \
        "ds_read_b128 %14, %16 offset:14336\n\t"                         \
        "ds_read_b128 %15, %16 offset:15360\n\t"                         \
        "s_waitcnt lgkmcnt(0)"                                           \
        : "=&v"(pv[0]), "=&v"(pv[1]), "=&v"(pv[2]), "=&v"(pv[3]),        \
          "=&v"(pv[4]), "=&v"(pv[5]), "=&v"(pv[6]), "=&v"(pv[7]),        \
          "=&v"(dv[0]), "=&v"(dv[1]), "=&v"(dv[2]), "=&v"(dv[3]),        \
          "=&v"(dv[4]), "=&v"(dv[5]), "=&v"(dv[6]), "=&v"(dv[7])         \
        : "v"(a) : "memory")

__device__ __forceinline__ void scan_chunk(const float* buf, int n, float& st,
                                           f32x4 (&sv)[8], float* sp)
{
    const float L2E = 1.44269504088896340736f;
    if (sp) {
        #pragma unroll
        for (int j = 0; j < 8; ++j)
            *(f32x4*)(sp + 4 * j) = sv[j];
    }
    unsigned a = (unsigned)(unsigned long long)(LdsFloat*)buf
               + (unsigned)(n * 16);
    f32x4 pv[8], dv[8];
    DS_READ_ALL(pv, dv, a);
    __builtin_amdgcn_sched_barrier(0);
    #pragma unroll
    for (int j = 0; j < 8; ++j) {
        #pragma unroll
        for (int i = 0; i < 4; ++i) {
            float d  = dv[j][i];
            float u  = st + d;                                  // off critical path
            float e  = __builtin_amdgcn_exp2f(fmaf(st, -L2E, -d * L2E));
            float r  = __builtin_amdgcn_rcpf(1.f + e);
            st = fmaf(u, r, pv[j][i]);
            sv[j][i] = st;
        }
    }
}

#define RP(c) (obase + (size_t)((((c) >> 1) * 64) + n) * Dn + ((c) & 1) * 32)
#define SP(c) (RP(c) + 128)

__global__ __launch_bounds__(64, 1)
void scan_kernel(float* __restrict__ O)
{
    __shared__ __align__(16) float buf[3][4096];   // 3 x 16KB

    const int b = blockIdx.x;
    const int n = threadIdx.x;
    float* obase = O + (size_t)b * Tn * Dn;

    float* b0 = buf[0];
    float* b1 = buf[1];
    float* b2 = buf[2];

    f32x4 sv[8];
    float st = 0.f;

    issue_chunk(b0, RP(0));                    // L0
    issue_chunk(b1, RP(1));                    // L1
    issue_chunk(b2, RP(2));                    // L2
    WAITV(32);                                 // drain L0
    scan_chunk(b0, n, st, sv, nullptr);        // c0
    { float* t = b0; b0 = b1; b1 = b2; b2 = t; }

    issue_chunk(b2, RP(3));                    // L3
    WAITV(32);                                 // drain L1
    scan_chunk(b0, n, st, sv, SP(0));          // c1
    { float* t = b0; b0 = b1; b1 = b2; b2 = t; }

    #pragma unroll 1
    for (int c = 2; c <= 125; ++c) {
        issue_chunk(b2, RP(c + 2));            // L_{c+2}
        WAITV(40);                             // drain L_c
        scan_chunk(b0, n, st, sv, SP(c - 1));
        { float* t = b0; b0 = b1; b1 = b2; b2 = t; }
    }

    WAITV(24);                                 // drain L126
    scan_chunk(b0, n, st, sv, SP(125));
    { float* t = b0; b0 = b1; b1 = b2; b2 = t; }

    WAITV(16);                                 // drain L127
    scan_chunk(b0, n, st, sv, SP(126));

    {
        float* sp = SP(127);
        #pragma unroll
        for (int j = 0; j < 8; ++j)
            *(f32x4*)(sp + 4 * j) = sv[j];
    }
}

#undef RP
#undef SP

// ---------------------------------------------------------------------------
// Kernel 3 (round 10): output projection as bf16x3 MFMA GEMM, in-place.
// grid (BT/64), block 256 (4 waves). Per block: one 64-row tile.
//   A = S (64t x 64n, bf16 hi/lo frags built from staged Ss — prep's verified
//       A-frag convention: lane=(m&15)|(kgrp<<4), 8 K-elems/lane)
//   B = out_w frags pre-split by prep0 into ws2 (prep's verified Bw
//       convention), DMA'd per wave: each wave owns 16 d-tiles, processed in
//       8 chunks of 2 d-tiles with a per-wave double-buffered global_load_lds
//       pipeline; counted s_waitcnt vmcnt(8) keeps ONLY the 8 newest DMAs
//       (stores always in the drain set -> robust ledger). Loop fully
//       unrolled so all register-array indices are static (rule #20).
// ---------------------------------------------------------------------------

#define DS_READ_B8(b00h, b00l, b01h, b01l, b10h, b10l, b11h, b11l, a)    \
    asm volatile(                                                        \
        "ds_read_b128 %0, %8 offset:0\n\t"                               \
        "ds_read_b128 %1, %8 offset:1024\n\t"                            \
        "ds_read_b128 %2, %8 offset:2048\n\t"                            \
        "ds_read_b128 %3, %8 offset:3072\n\t"                            \
        "ds_read_b128 %4, %8 offset:4096\n\t"                            \
        "ds_read_b128 %5, %8 offset:5120\n\t"                            \
        "ds_read_b128 %6, %8 offset:6144\n\t"                            \
        "ds_read_b128 %7, %8 offset:7168\n\t"                            \
        "s_waitcnt lgkmcnt(0)"                                           \
        : "=&v"(b00h), "=&v"(b00l), "=&v"(b01h), "=&v"(b01l),            \
          "=&v"(b10h), "=&v"(b10l), "=&v"(b11h), "=&v"(b11l)             \
        : "v"(a) : "memory")

__global__ __launch_bounds__(256)
void out_kernel(const unsigned short* __restrict__ ws,
                const float* __restrict__ out_b, float* __restrict__ O)
{
    __shared__ float  Ss[64][Nn + 4];        // staged S, [t][n], pad 68
    __shared__ bf16x8 AfH[8][64], AfL[8][64];// A-frags, grp = kh*4+tt
    __shared__ bf16x8 Bb[4][2][8][64];       // [wave][buf][grp][lane], 64KB

    const int tid = threadIdx.x;
    const int r0  = blockIdx.x * 64;
    const int l   = tid & 63;
    const int w   = tid >> 6;
    const unsigned short* ws2 = ws + 163840;

    // ---- stage S (verified): element (t=r0+tl, n) at O[(r0+n)*Dn+128+tl]
    for (int idx = tid; idx < 64 * 16; idx += 256) {
        int nn = idx >> 4, tg = idx & 15;
        float4 v = *(const float4*)&O[(size_t)(r0 + nn) * Dn + 128 + 4 * tg];
        Ss[4 * tg + 0][nn] = v.x;
        Ss[4 * tg + 1][nn] = v.y;
        Ss[4 * tg + 2][nn] = v.z;
        Ss[4 * tg + 3][nn] = v.w;
    }
    __syncthreads();

    // ---- build A-frags (512 slots, 2 per thread), prep's A convention
    #pragma unroll
    for (int s2 = 0; s2 < 2; ++s2) {
        int slot = tid + s2 * 256;
        int grp = slot >> 6, ln = slot & 63;
        int tt = grp & 3, kh = grp >> 2;
        int t  = tt * 16 + (ln & 15);
        int n0 = kh * 32 + (ln >> 4) * 8;
        float4 q0 = *(const float4*)&Ss[t][n0];
        float4 q1 = *(const float4*)&Ss[t][n0 + 4];
        float v[8] = {q0.x, q0.y, q0.z, q0.w, q1.x, q1.y, q1.z, q1.w};
        bf16x8 fh, fl;
        #pragma unroll
        for (int k = 0; k < 8; ++k) {
            unsigned short h = bf16_rne(v[k]);
            float hf = __uint_as_float((unsigned)h << 16);
            fh[k] = (short)h; fl[k] = (short)bf16_rne(v[k] - hf);
        }
        AfH[grp][ln] = fh; AfL[grp][ln] = fl;
    }
    __syncthreads();

    // ---- per-wave: A-frags + out_b to registers
    bf16x8 ah[4][2], al[4][2];
    #pragma unroll
    for (int tt = 0; tt < 4; ++tt)
        #pragma unroll
        for (int kh = 0; kh < 2; ++kh) {
            ah[tt][kh] = AfH[kh * 4 + tt][l];
            al[tt][kh] = AfL[kh * 4 + tt][l];
        }
    float ob[16];
    #pragma unroll
    for (int k = 0; k < 16; ++k)
        ob[k] = out_b[(w * 16 + k) * 16 + (l & 15)];

    const unsigned bbase = (unsigned)(unsigned long long)(LdsFloat*)&Bb[w][0][0][0]
                         + (unsigned)(l * 16);
    const f32x4 z4 = {0.f, 0.f, 0.f, 0.f};

    // ---- DMA chunk 0 (dt = w*16, w*16+1)
    {
        const unsigned short* p = ws2 + (size_t)(w * 16) * 2048 + l * 8;
        #pragma unroll
        for (int g = 0; g < 8; ++g)
            __builtin_amdgcn_global_load_lds((GVoid*)(p + (g >> 2) * 2048 + (g & 3) * 512),
                                             (LVoid*)&Bb[w][0][g][0], 16, 0, 0);
    }

    // ---- 8 chunks, fully unrolled (static indices everywhere)
    #pragma unroll
    for (int i = 0; i < 8; ++i) {
        if (i < 7) {
            const unsigned short* p = ws2 + (size_t)(w * 16 + 2 * (i + 1)) * 2048 + l * 8;
            #pragma unroll
            for (int g = 0; g < 8; ++g)
                __builtin_amdgcn_global_load_lds((GVoid*)(p + (g >> 2) * 2048 + (g & 3) * 512),
                                                 (LVoid*)&Bb[w][(i + 1) & 1][g][0], 16, 0, 0);
            WAITV(8);    // keep only the 8 just-issued; drains chunk i's DMA + old stores
        } else {
            WAITV(0);
        }
        unsigned a = bbase + (unsigned)((i & 1) * 8192);
        bf16x8 bh[2][2], bl[2][2];
        DS_READ_B8(bh[0][0], bl[0][0], bh[0][1], bl[0][1],
                   bh[1][0], bl[1][0], bh[1][1], bl[1][1], a);
        __builtin_amdgcn_sched_barrier(0);

        #pragma unroll
        for (int dto = 0; dto < 2; ++dto) {
            const int dcol = (w * 16 + 2 * i + dto) * 16 + (l & 15);
            const float bbv = ob[2 * i + dto];
            #pragma unroll
            for (int tt = 0; tt < 4; ++tt) {
                f32x4 acc = z4;
                #pragma unroll
                for (int kh = 0; kh < 2; ++kh) {
                    acc = __builtin_amdgcn_mfma_f32_16x16x32_bf16(ah[tt][kh], bh[dto][kh], acc, 0, 0, 0);
                    acc = __builtin_amdgcn_mfma_f32_16x16x32_bf16(al[tt][kh], bh[dto][kh], acc, 0, 0, 0);
                    acc = __builtin_amdgcn_mfma_f32_16x16x32_bf16(ah[tt][kh], bl[dto][kh], acc, 0, 0, 0);
                }
                #pragma unroll
                for (int j = 0; j < 4; ++j) {
                    int row = tt * 16 + (l >> 4) * 4 + j;
                    O[(size_t)(r0 + row) * Dn + dcol] = acc[j] + bbv;
                }
            }
        }
    }
}

extern "C" void kernel_launch(void* const* d_in, const int* in_sizes, int n_in,
                              void* d_out, int out_size, void* d_ws, size_t ws_size,
                              hipStream_t stream)
{
    const float* x      = (const float*)d_in[0];
    const float* conv_w = (const float*)d_in[1];
    const float* in_w   = (const float*)d_in[2];
    const float* in_b   = (const float*)d_in[3];
    const float* dt_w   = (const float*)d_in[4];
    const float* dt_b   = (const float*)d_in[5];
    const float* tr_w   = (const float*)d_in[6];
    const float* out_w  = (const float*)d_in[7];
    const float* out_b  = (const float*)d_in[8];
    float* O = (float*)d_out;
    unsigned short* ws = (unsigned short*)d_ws;   // needs 589,824 B
    (void)ws_size;

    prep0_kernel<<<dim3(96), 256, 0, stream>>>(in_w, dt_w, out_w, ws);

    dim3 g1(Tn / TT2, Bn);
    prep_kernel<<<g1, 128, 0, stream>>>(x, conv_w, ws, in_b, dt_b, tr_w, O);

    scan_kernel<<<dim3(Bn), 64, 0, stream>>>(O);

    out_kernel<<<dim3((Bn * Tn) / 64), 256, 0, stream>>>(ws, out_b, O);
}